// Round 1
// baseline (6163.470 us; speedup 1.0000x reference)
//
#include <hip/hip_runtime.h>
#include <math.h>

#define N_NODES 100000
#define N_EDGES 1600000

static inline int cdiv(long a, long b) { return (int)((a + b - 1) / b); }

// ---------------- GEMM: C[i,m] = sum_k A[i,k] * B[k,m] (or B[m,k] if BT) ----
template <int K, int M, bool BT>
__global__ __launch_bounds__(256) void gemm_k(const float* __restrict__ A,
                                              const float* __restrict__ B,
                                              float* __restrict__ C, int n) {
    int idx = blockIdx.x * 256 + threadIdx.x;
    if (idx >= n * M) return;
    int row = idx / M;
    int col = idx - row * M;
    const float* a = A + (size_t)row * K;
    float acc = 0.f;
#pragma unroll 8
    for (int k = 0; k < K; ++k) {
        float b = BT ? B[(size_t)col * K + k] : B[(size_t)k * M + col];
        acc += a[k] * b;
    }
    C[idx] = acc;
}

// ---------------- attention feature dots: f1 = H.va, f2 = H.vb --------------
__global__ __launch_bounds__(256) void attn_f_kernel(const float* __restrict__ H,
                                                     const float* __restrict__ va,
                                                     const float* __restrict__ vb,
                                                     float* __restrict__ f1,
                                                     float* __restrict__ f2) {
    int wid = (blockIdx.x * 256 + threadIdx.x) >> 6;  // one wave per row
    int lane = threadIdx.x & 63;
    if (wid >= N_NODES) return;
    const float* h = H + (size_t)wid * 128;
    float a = 0.f, b = 0.f;
#pragma unroll
    for (int k = lane; k < 128; k += 64) {
        float x = h[k];
        a += x * va[k];
        b += x * vb[k];
    }
#pragma unroll
    for (int off = 32; off > 0; off >>= 1) {
        a += __shfl_down(a, off);
        b += __shfl_down(b, off);
    }
    if (lane == 0) { f1[wid] = a; f2[wid] = b; }
}

// ---------------- edge exp + row-sum --------------------------------------
__global__ __launch_bounds__(256) void edge_exp_kernel(const int* __restrict__ rows,
                                                       const int* __restrict__ cols,
                                                       const float* __restrict__ f1,
                                                       const float* __restrict__ f2,
                                                       float* __restrict__ cval,
                                                       float* __restrict__ s) {
    int e = blockIdx.x * 256 + threadIdx.x;
    if (e >= N_EDGES) return;
    int r = rows[e];
    float v = __expf(f1[r] + f2[cols[e]]);
    cval[e] = v;
    atomicAdd(&s[r], v);
}

__global__ __launch_bounds__(256) void edge_norm_kernel(const int* __restrict__ rows,
                                                        float* __restrict__ cval,
                                                        const float* __restrict__ s) {
    int e = blockIdx.x * 256 + threadIdx.x;
    if (e >= N_EDGES) return;
    cval[e] = cval[e] / s[rows[e]];
}

// ---------------- SpMM (atomic scatter): out[r] += scale*c[e]*H[c] ---------
__global__ __launch_bounds__(256) void spmm_kernel(const int* __restrict__ rows,
                                                   const int* __restrict__ cols,
                                                   const float* __restrict__ cval,
                                                   float scale,
                                                   const float* __restrict__ H,
                                                   float* __restrict__ out) {
    int e = blockIdx.x * 2 + (threadIdx.x >> 7);
    int d = threadIdx.x & 127;
    if (e >= N_EDGES) return;
    int r = rows[e];
    int c = cols[e];
    float v = scale * cval[e];
    atomicAdd(&out[(size_t)r * 128 + d], v * H[(size_t)c * 128 + d]);
}

// ---------------- ELU in place ---------------------------------------------
__global__ __launch_bounds__(256) void elu_kernel(float* __restrict__ x, int n) {
    int i = blockIdx.x * 256 + threadIdx.x;
    if (i >= n) return;
    float v = x[i];
    x[i] = v > 0.f ? v : expm1f(v);
}

// ---------------- reductions -----------------------------------------------
// sum((a-b)^2) if b != nullptr, else sum(a^2); atomicAdd into acc
__global__ __launch_bounds__(256) void sq_reduce_kernel(const float* __restrict__ a,
                                                        const float* __restrict__ b,
                                                        float* __restrict__ acc, int n) {
    __shared__ float sm[4];
    float s = 0.f;
    for (int i = blockIdx.x * 256 + threadIdx.x; i < n; i += gridDim.x * 256) {
        float d = b ? (a[i] - b[i]) : a[i];
        s += d * d;
    }
#pragma unroll
    for (int off = 32; off > 0; off >>= 1) s += __shfl_down(s, off);
    int lane = threadIdx.x & 63, w = threadIdx.x >> 6;
    if (lane == 0) sm[w] = s;
    __syncthreads();
    if (threadIdx.x == 0) {
        float t = sm[0] + sm[1] + sm[2] + sm[3];
        atomicAdd(acc, t);
    }
}

__global__ void finalize_kernel(const float* __restrict__ acc, float* __restrict__ out) {
    out[0] = sqrtf(acc[0]) + 1e-4f * (acc[1] + acc[2]);
}

extern "C" void kernel_launch(void* const* d_in, const int* in_sizes, int n_in,
                              void* d_out, int out_size, void* d_ws, size_t ws_size,
                              hipStream_t stream) {
    const float* X    = (const float*)d_in[0];
    const float* W0   = (const float*)d_in[1];
    const float* W1   = (const float*)d_in[2];
    const float* v00  = (const float*)d_in[3];
    const float* v01  = (const float*)d_in[4];
    const float* pv00 = (const float*)d_in[5];
    const float* pv01 = (const float*)d_in[6];
    const int* rows   = (const int*)d_in[7];
    const int* cols   = (const int*)d_in[8];
    const int* prows  = (const int*)d_in[9];
    const int* pcols  = (const int*)d_in[10];

    float* out  = (float*)d_out;
    float* Henc = out + 1;                                  // N x 64
    float* Xrec = out + 1 + (size_t)N_NODES * 64;           // N x 256

    // bufA (N x 128) aliased into the X_ output region (dead before X_ write)
    float* bufA = Xrec;

    float* ws   = (float*)d_ws;
    float* bufB = ws;                                       // N x 128 (accumulator)
    float* c1   = bufB + (size_t)N_NODES * 128;             // E
    float* c2   = c1 + N_EDGES;                             // E
    float* f1   = c2 + N_EDGES;                             // N
    float* f2   = f1 + N_NODES;
    float* pf1  = f2 + N_NODES;
    float* pf2  = pf1 + N_NODES;
    float* s1   = pf2 + N_NODES;                            // N
    float* s2   = s1 + N_NODES;                             // N
    float* acc  = s2 + N_NODES;                             // 3

    const int n = N_NODES;

    // 1. H1 = X @ W0  -> bufA
    gemm_k<256, 128, false><<<cdiv((long)n * 128, 256), 256, 0, stream>>>(X, W0, bufA, n);

    // zero s1, s2, acc (contiguous)
    hipMemsetAsync(s1, 0, (2 * (size_t)N_NODES + 3) * sizeof(float), stream);

    // 2. attention feature dots
    attn_f_kernel<<<cdiv(n, 4), 256, 0, stream>>>(bufA, v00, v01, f1, f2);
    attn_f_kernel<<<cdiv(n, 4), 256, 0, stream>>>(bufA, pv00, pv01, pf1, pf2);

    // 3. edge exp + row sums
    edge_exp_kernel<<<cdiv(N_EDGES, 256), 256, 0, stream>>>(rows, cols, f1, f2, c1, s1);
    edge_exp_kernel<<<cdiv(N_EDGES, 256), 256, 0, stream>>>(prows, pcols, pf1, pf2, c2, s2);
    edge_norm_kernel<<<cdiv(N_EDGES, 256), 256, 0, stream>>>(rows, c1, s1);
    edge_norm_kernel<<<cdiv(N_EDGES, 256), 256, 0, stream>>>(prows, c2, s2);

    // 4. encoder SpMM: bufB = 0.2*spmm(adj1, c1, H1) + 0.8*spmm(adj2, c2, H1)
    hipMemsetAsync(bufB, 0, (size_t)N_NODES * 128 * sizeof(float), stream);
    spmm_kernel<<<cdiv(N_EDGES, 2), 256, 0, stream>>>(rows, cols, c1, 0.2f, bufA, bufB);
    spmm_kernel<<<cdiv(N_EDGES, 2), 256, 0, stream>>>(prows, pcols, c2, 0.8f, bufA, bufB);

    // 5. ELU
    elu_kernel<<<cdiv((long)n * 128, 256), 256, 0, stream>>>(bufB, n * 128);

    // 6. Henc = bufB @ W1  -> d_out
    gemm_k<128, 64, false><<<cdiv((long)n * 64, 256), 256, 0, stream>>>(bufB, W1, Henc, n);

    // 7. D0 = Henc @ W1^T -> bufA
    gemm_k<64, 128, true><<<cdiv((long)n * 128, 256), 256, 0, stream>>>(Henc, W1, bufA, n);

    // 8. decoder SpMM -> bufB
    hipMemsetAsync(bufB, 0, (size_t)N_NODES * 128 * sizeof(float), stream);
    spmm_kernel<<<cdiv(N_EDGES, 2), 256, 0, stream>>>(rows, cols, c1, 0.2f, bufA, bufB);
    spmm_kernel<<<cdiv(N_EDGES, 2), 256, 0, stream>>>(prows, pcols, c2, 0.8f, bufA, bufB);

    // 9. ELU
    elu_kernel<<<cdiv((long)n * 128, 256), 256, 0, stream>>>(bufB, n * 128);

    // 10. X_ = bufB @ W0^T -> Xrec (bufA region now dead)
    gemm_k<128, 256, true><<<cdiv((long)n * 256, 256), 256, 0, stream>>>(bufB, W0, Xrec, n);

    // 11. loss
    sq_reduce_kernel<<<2048, 256, 0, stream>>>(X, Xrec, acc + 0, n * 256);
    sq_reduce_kernel<<<16, 256, 0, stream>>>(W0, nullptr, acc + 1, 256 * 128);
    sq_reduce_kernel<<<4, 256, 0, stream>>>(W1, nullptr, acc + 2, 128 * 64);
    finalize_kernel<<<1, 1, 0, stream>>>(acc, out);
}

// Round 2
// 3534.330 us; speedup vs baseline: 1.7439x; 1.7439x over previous
//
#include <hip/hip_runtime.h>
#include <math.h>

#define N_NODES 100000
#define N_EDGES 1600000

static inline int cdiv(long a, long b) { return (int)((a + b - 1) / b); }

// ---------------- tiled GEMM: C[i,m] = sum_k A[i,k] * B[k,m], B row-major KxM
// Block: 256 threads, covers R=1024/M rows x M cols. K chunked at KC=32,
// B chunk staged in LDS (<=32KB), A chunk in registers (wave-uniform loads).
// A4/C4: whether A/C base pointers are 16B-aligned (d_out offsets are not).
template <int K, int M, bool A4, bool C4>
__global__ __launch_bounds__(256) void gemm_tiled(const float* __restrict__ A,
                                                  const float* __restrict__ B,
                                                  float* __restrict__ C) {
    constexpr int KC = 32;
    constexpr int R = 1024 / M;   // rows per block
    constexpr int TPR = M / 4;    // threads per row
    __shared__ float Blds[KC * M];
    const int trow = threadIdx.x / TPR;
    const int tcol = threadIdx.x % TPR;
    const int r = blockIdx.x * R + trow;
    float acc0 = 0.f, acc1 = 0.f, acc2 = 0.f, acc3 = 0.f;
    for (int k0 = 0; k0 < K; k0 += KC) {
        // cooperative B chunk load (contiguous KC*M floats)
        const float4* Bsrc = reinterpret_cast<const float4*>(B + (size_t)k0 * M);
        float4* Bdst = reinterpret_cast<float4*>(Blds);
#pragma unroll
        for (int i = 0; i < (KC * M / 4) / 256; ++i)
            Bdst[i * 256 + threadIdx.x] = Bsrc[i * 256 + threadIdx.x];
        __syncthreads();
        // A chunk into registers (uniform across threads of same row -> L1 broadcast)
        float a[KC];
        if (A4) {
            const float4* Asrc = reinterpret_cast<const float4*>(A + (size_t)r * K + k0);
#pragma unroll
            for (int i = 0; i < KC / 4; ++i) {
                float4 v = Asrc[i];
                a[4 * i] = v.x; a[4 * i + 1] = v.y; a[4 * i + 2] = v.z; a[4 * i + 3] = v.w;
            }
        } else {
#pragma unroll
            for (int i = 0; i < KC; ++i) a[i] = A[(size_t)r * K + k0 + i];
        }
#pragma unroll
        for (int kk = 0; kk < KC; ++kk) {
            const float* brow = Blds + kk * M + tcol * 4;
            acc0 += a[kk] * brow[0];
            acc1 += a[kk] * brow[1];
            acc2 += a[kk] * brow[2];
            acc3 += a[kk] * brow[3];
        }
        __syncthreads();
    }
    float* c = C + (size_t)r * M + tcol * 4;
    if (C4) {
        float4 v = make_float4(acc0, acc1, acc2, acc3);
        *reinterpret_cast<float4*>(c) = v;
    } else {
        c[0] = acc0; c[1] = acc1; c[2] = acc2; c[3] = acc3;
    }
}

// ---------------- small matrix transpose: out[c][r] = in[r][c] --------------
__global__ __launch_bounds__(256) void transpose_kernel(const float* __restrict__ in,
                                                        float* __restrict__ out,
                                                        int rows, int cols) {
    int i = blockIdx.x * 256 + threadIdx.x;
    if (i >= rows * cols) return;
    int r = i / cols, c = i - r * cols;
    out[c * rows + r] = in[i];
}

// ---------------- attention feature dots: f1 = H.va, f2 = H.vb --------------
__global__ __launch_bounds__(256) void attn_f_kernel(const float* __restrict__ H,
                                                     const float* __restrict__ va,
                                                     const float* __restrict__ vb,
                                                     float* __restrict__ f1,
                                                     float* __restrict__ f2) {
    int wid = (blockIdx.x * 256 + threadIdx.x) >> 6;  // one wave per row
    int lane = threadIdx.x & 63;
    if (wid >= N_NODES) return;
    const float* h = H + (size_t)wid * 128;
    float a = 0.f, b = 0.f;
#pragma unroll
    for (int k = lane; k < 128; k += 64) {
        float x = h[k];
        a += x * va[k];
        b += x * vb[k];
    }
#pragma unroll
    for (int off = 32; off > 0; off >>= 1) {
        a += __shfl_down(a, off);
        b += __shfl_down(b, off);
    }
    if (lane == 0) { f1[wid] = a; f2[wid] = b; }
}

// ---------------- edge exp + row-sum --------------------------------------
__global__ __launch_bounds__(256) void edge_exp_kernel(const int* __restrict__ rows,
                                                       const int* __restrict__ cols,
                                                       const float* __restrict__ f1,
                                                       const float* __restrict__ f2,
                                                       float* __restrict__ cval,
                                                       float* __restrict__ s) {
    int e = blockIdx.x * 256 + threadIdx.x;
    if (e >= N_EDGES) return;
    int r = rows[e];
    float v = __expf(f1[r] + f2[cols[e]]);
    cval[e] = v;
    atomicAdd(&s[r], v);
}

__global__ __launch_bounds__(256) void edge_norm_kernel(const int* __restrict__ rows,
                                                        float* __restrict__ cval,
                                                        const float* __restrict__ s) {
    int e = blockIdx.x * 256 + threadIdx.x;
    if (e >= N_EDGES) return;
    cval[e] = cval[e] / s[rows[e]];
}

// ---------------- SpMM (atomic scatter): out[r] += scale*c[e]*H[c] ---------
__global__ __launch_bounds__(256) void spmm_kernel(const int* __restrict__ rows,
                                                   const int* __restrict__ cols,
                                                   const float* __restrict__ cval,
                                                   float scale,
                                                   const float* __restrict__ H,
                                                   float* __restrict__ out) {
    int e = blockIdx.x * 2 + (threadIdx.x >> 7);
    int d = threadIdx.x & 127;
    if (e >= N_EDGES) return;
    int r = rows[e];
    int c = cols[e];
    float v = scale * cval[e];
    atomicAdd(&out[(size_t)r * 128 + d], v * H[(size_t)c * 128 + d]);
}

// ---------------- ELU in place ---------------------------------------------
__global__ __launch_bounds__(256) void elu_kernel(float* __restrict__ x, int n) {
    int i = blockIdx.x * 256 + threadIdx.x;
    if (i >= n) return;
    float v = x[i];
    x[i] = v > 0.f ? v : expm1f(v);
}

// ---------------- reductions -----------------------------------------------
__global__ __launch_bounds__(256) void sq_reduce_kernel(const float* __restrict__ a,
                                                        const float* __restrict__ b,
                                                        float* __restrict__ acc, int n) {
    __shared__ float sm[4];
    float s = 0.f;
    for (int i = blockIdx.x * 256 + threadIdx.x; i < n; i += gridDim.x * 256) {
        float d = b ? (a[i] - b[i]) : a[i];
        s += d * d;
    }
#pragma unroll
    for (int off = 32; off > 0; off >>= 1) s += __shfl_down(s, off);
    int lane = threadIdx.x & 63, w = threadIdx.x >> 6;
    if (lane == 0) sm[w] = s;
    __syncthreads();
    if (threadIdx.x == 0) {
        float t = sm[0] + sm[1] + sm[2] + sm[3];
        atomicAdd(acc, t);
    }
}

__global__ void finalize_kernel(const float* __restrict__ acc, float* __restrict__ out) {
    out[0] = sqrtf(acc[0]) + 1e-4f * (acc[1] + acc[2]);
}

extern "C" void kernel_launch(void* const* d_in, const int* in_sizes, int n_in,
                              void* d_out, int out_size, void* d_ws, size_t ws_size,
                              hipStream_t stream) {
    const float* X    = (const float*)d_in[0];
    const float* W0   = (const float*)d_in[1];
    const float* W1   = (const float*)d_in[2];
    const float* v00  = (const float*)d_in[3];
    const float* v01  = (const float*)d_in[4];
    const float* pv00 = (const float*)d_in[5];
    const float* pv01 = (const float*)d_in[6];
    const int* rows   = (const int*)d_in[7];
    const int* cols   = (const int*)d_in[8];
    const int* prows  = (const int*)d_in[9];
    const int* pcols  = (const int*)d_in[10];

    float* out  = (float*)d_out;
    float* Henc = out + 1;                                  // N x 64 (base NOT 16B-aligned)
    float* Xrec = out + 1 + (size_t)N_NODES * 64;           // N x 256 (base NOT 16B-aligned)

    // bufA (N x 128) aliased into the X_ region, re-based to a 16B-aligned
    // offset (out+6400004). Dead before X_ is written in step 10.
    float* bufA = out + 6400004;

    float* ws   = (float*)d_ws;
    float* bufB = ws;                                       // N x 128 (accumulator)
    float* c1   = bufB + (size_t)N_NODES * 128;             // E
    float* c2   = c1 + N_EDGES;                             // E
    float* f1   = c2 + N_EDGES;                             // N
    float* f2   = f1 + N_NODES;
    float* pf1  = f2 + N_NODES;
    float* pf2  = pf1 + N_NODES;
    float* s1   = pf2 + N_NODES;                            // N
    float* s2   = s1 + N_NODES;                             // N
    float* acc  = s2 + N_NODES;                             // 3 (keep block of 4 for alignment)
    float* W1T  = acc + 4;                                  // 64 x 128
    float* W0T  = W1T + 64 * 128;                           // 128 x 256

    const int n = N_NODES;

    // 0. weight transposes (tiny)
    transpose_kernel<<<cdiv(128 * 64, 256), 256, 0, stream>>>(W1, W1T, 128, 64);
    transpose_kernel<<<cdiv(256 * 128, 256), 256, 0, stream>>>(W0, W0T, 256, 128);

    // 1. H1 = X @ W0  -> bufA
    gemm_tiled<256, 128, true, true><<<n / 8, 256, 0, stream>>>(X, W0, bufA);

    // zero s1, s2, acc (contiguous)
    hipMemsetAsync(s1, 0, (2 * (size_t)N_NODES + 4) * sizeof(float), stream);

    // 2. attention feature dots
    attn_f_kernel<<<cdiv(n, 4), 256, 0, stream>>>(bufA, v00, v01, f1, f2);
    attn_f_kernel<<<cdiv(n, 4), 256, 0, stream>>>(bufA, pv00, pv01, pf1, pf2);

    // 3. edge exp + row sums
    edge_exp_kernel<<<cdiv(N_EDGES, 256), 256, 0, stream>>>(rows, cols, f1, f2, c1, s1);
    edge_exp_kernel<<<cdiv(N_EDGES, 256), 256, 0, stream>>>(prows, pcols, pf1, pf2, c2, s2);
    edge_norm_kernel<<<cdiv(N_EDGES, 256), 256, 0, stream>>>(rows, c1, s1);
    edge_norm_kernel<<<cdiv(N_EDGES, 256), 256, 0, stream>>>(prows, c2, s2);

    // 4. encoder SpMM: bufB = 0.2*spmm(adj1, c1, H1) + 0.8*spmm(adj2, c2, H1)
    hipMemsetAsync(bufB, 0, (size_t)N_NODES * 128 * sizeof(float), stream);
    spmm_kernel<<<cdiv(N_EDGES, 2), 256, 0, stream>>>(rows, cols, c1, 0.2f, bufA, bufB);
    spmm_kernel<<<cdiv(N_EDGES, 2), 256, 0, stream>>>(prows, pcols, c2, 0.8f, bufA, bufB);

    // 5. ELU
    elu_kernel<<<cdiv((long)n * 128, 256), 256, 0, stream>>>(bufB, n * 128);

    // 6. Henc = bufB @ W1  -> d_out (C base misaligned)
    gemm_tiled<128, 64, true, false><<<n / 16, 256, 0, stream>>>(bufB, W1, Henc);

    // 7. D0 = Henc @ W1^T -> bufA (A base misaligned)
    gemm_tiled<64, 128, false, true><<<n / 8, 256, 0, stream>>>(Henc, W1T, bufA);

    // 8. decoder SpMM -> bufB
    hipMemsetAsync(bufB, 0, (size_t)N_NODES * 128 * sizeof(float), stream);
    spmm_kernel<<<cdiv(N_EDGES, 2), 256, 0, stream>>>(rows, cols, c1, 0.2f, bufA, bufB);
    spmm_kernel<<<cdiv(N_EDGES, 2), 256, 0, stream>>>(prows, pcols, c2, 0.8f, bufA, bufB);

    // 9. ELU
    elu_kernel<<<cdiv((long)n * 128, 256), 256, 0, stream>>>(bufB, n * 128);

    // 10. X_ = bufB @ W0^T -> Xrec (bufA region now dead; C base misaligned)
    gemm_tiled<128, 256, true, false><<<n / 4, 256, 0, stream>>>(bufB, W0T, Xrec);

    // 11. loss
    sq_reduce_kernel<<<2048, 256, 0, stream>>>(X, Xrec, acc + 0, n * 256);
    sq_reduce_kernel<<<16, 256, 0, stream>>>(W0, nullptr, acc + 1, 256 * 128);
    sq_reduce_kernel<<<4, 256, 0, stream>>>(W1, nullptr, acc + 2, 128 * 64);
    finalize_kernel<<<1, 1, 0, stream>>>(acc, out);
}

// Round 3
// 1587.761 us; speedup vs baseline: 3.8819x; 2.2260x over previous
//
#include <hip/hip_runtime.h>
#include <math.h>

#define N_NODES 100000
#define N_EDGES 1600000
#define SCAN_NB 128   // blocks in scan kernels
#define SCAN_CH 4     // elements per thread in scan (128*256*4 = 131072 >= N+1)

static inline int cdiv(long a, long b) { return (int)((a + b - 1) / b); }

// ---------------- tiled GEMM: C[i,m] = sum_k A[i,k] * B[k,m], B row-major KxM
template <int K, int M, bool A4, bool C4>
__global__ __launch_bounds__(256) void gemm_tiled(const float* __restrict__ A,
                                                  const float* __restrict__ B,
                                                  float* __restrict__ C) {
    constexpr int KC = 32;
    constexpr int R = 1024 / M;   // rows per block
    constexpr int TPR = M / 4;    // threads per row
    __shared__ float Blds[KC * M];
    const int trow = threadIdx.x / TPR;
    const int tcol = threadIdx.x % TPR;
    const int r = blockIdx.x * R + trow;
    float acc0 = 0.f, acc1 = 0.f, acc2 = 0.f, acc3 = 0.f;
    for (int k0 = 0; k0 < K; k0 += KC) {
        const float4* Bsrc = reinterpret_cast<const float4*>(B + (size_t)k0 * M);
        float4* Bdst = reinterpret_cast<float4*>(Blds);
#pragma unroll
        for (int i = 0; i < (KC * M / 4) / 256; ++i)
            Bdst[i * 256 + threadIdx.x] = Bsrc[i * 256 + threadIdx.x];
        __syncthreads();
        float a[KC];
        if (A4) {
            const float4* Asrc = reinterpret_cast<const float4*>(A + (size_t)r * K + k0);
#pragma unroll
            for (int i = 0; i < KC / 4; ++i) {
                float4 v = Asrc[i];
                a[4 * i] = v.x; a[4 * i + 1] = v.y; a[4 * i + 2] = v.z; a[4 * i + 3] = v.w;
            }
        } else {
#pragma unroll
            for (int i = 0; i < KC; ++i) a[i] = A[(size_t)r * K + k0 + i];
        }
#pragma unroll
        for (int kk = 0; kk < KC; ++kk) {
            const float* brow = Blds + kk * M + tcol * 4;
            acc0 += a[kk] * brow[0];
            acc1 += a[kk] * brow[1];
            acc2 += a[kk] * brow[2];
            acc3 += a[kk] * brow[3];
        }
        __syncthreads();
    }
    float* c = C + (size_t)r * M + tcol * 4;
    if (C4) {
        *reinterpret_cast<float4*>(c) = make_float4(acc0, acc1, acc2, acc3);
    } else {
        c[0] = acc0; c[1] = acc1; c[2] = acc2; c[3] = acc3;
    }
}

// ---------------- small matrix transpose ------------------------------------
__global__ __launch_bounds__(256) void transpose_kernel(const float* __restrict__ in,
                                                        float* __restrict__ out,
                                                        int rows, int cols) {
    int i = blockIdx.x * 256 + threadIdx.x;
    if (i >= rows * cols) return;
    int r = i / cols, c = i - r * cols;
    out[c * rows + r] = in[i];
}

// ---------------- attention feature dots: all 4 at once ---------------------
__global__ __launch_bounds__(256) void attn_f4_kernel(const float* __restrict__ H,
                                                      const float* __restrict__ va,
                                                      const float* __restrict__ vb,
                                                      const float* __restrict__ pva,
                                                      const float* __restrict__ pvb,
                                                      float* __restrict__ f1,
                                                      float* __restrict__ f2,
                                                      float* __restrict__ pf1,
                                                      float* __restrict__ pf2) {
    int wid = (blockIdx.x * 256 + threadIdx.x) >> 6;  // one wave per row
    int lane = threadIdx.x & 63;
    if (wid >= N_NODES) return;
    const float* h = H + (size_t)wid * 128;
    float a = 0.f, b = 0.f, pa = 0.f, pb = 0.f;
#pragma unroll
    for (int k = lane; k < 128; k += 64) {
        float x = h[k];
        a += x * va[k];
        b += x * vb[k];
        pa += x * pva[k];
        pb += x * pvb[k];
    }
#pragma unroll
    for (int off = 32; off > 0; off >>= 1) {
        a += __shfl_down(a, off);
        b += __shfl_down(b, off);
        pa += __shfl_down(pa, off);
        pb += __shfl_down(pb, off);
    }
    if (lane == 0) { f1[wid] = a; f2[wid] = b; pf1[wid] = pa; pf2[wid] = pb; }
}

// ---------------- CSR build ------------------------------------------------
__global__ __launch_bounds__(256) void hist_kernel(const int* __restrict__ rows,
                                                   int* __restrict__ deg) {
    int e = blockIdx.x * 256 + threadIdx.x;
    if (e >= N_EDGES) return;
    atomicAdd(&deg[rows[e]], 1);
}

// scan step 1: per-block sums of deg
__global__ __launch_bounds__(256) void scan1_kernel(const int* __restrict__ deg,
                                                    int* __restrict__ bsum) {
    __shared__ int sm[256];
    int base = (blockIdx.x * 256 + threadIdx.x) * SCAN_CH;
    int s = 0;
#pragma unroll
    for (int i = 0; i < SCAN_CH; ++i) {
        int idx = base + i;
        if (idx < N_NODES) s += deg[idx];
    }
    sm[threadIdx.x] = s;
    __syncthreads();
    for (int off = 128; off > 0; off >>= 1) {
        if (threadIdx.x < off) sm[threadIdx.x] += sm[threadIdx.x + off];
        __syncthreads();
    }
    if (threadIdx.x == 0) bsum[blockIdx.x] = sm[0];
}

// scan step 2: exclusive scan of bsum[SCAN_NB] (single tiny block)
__global__ void scan2_kernel(int* __restrict__ bsum) {
    if (threadIdx.x != 0) return;
    int run = 0;
    for (int i = 0; i < SCAN_NB; ++i) {
        int t = bsum[i];
        bsum[i] = run;
        run += t;
    }
}

// scan step 3: write exclusive prefix rp[0..N], rp[N]=E
__global__ __launch_bounds__(256) void scan3_kernel(const int* __restrict__ deg,
                                                    const int* __restrict__ bsum,
                                                    int* __restrict__ rp) {
    __shared__ int sm[256];
    int base = (blockIdx.x * 256 + threadIdx.x) * SCAN_CH;
    int s = 0;
#pragma unroll
    for (int i = 0; i < SCAN_CH; ++i) {
        int idx = base + i;
        if (idx < N_NODES) s += deg[idx];
    }
    sm[threadIdx.x] = s;
    __syncthreads();
    if (threadIdx.x == 0) {
        int run = bsum[blockIdx.x];
        for (int t = 0; t < 256; ++t) { int tmp = sm[t]; sm[t] = run; run += tmp; }
    }
    __syncthreads();
    int off = sm[threadIdx.x];
#pragma unroll
    for (int i = 0; i < SCAN_CH; ++i) {
        int idx = base + i;
        if (idx < N_NODES) { rp[idx] = off; off += deg[idx]; }
        else if (idx == N_NODES) rp[idx] = off;
    }
}

// scatter edges into CSR slots; store col and unnormalized exp value
__global__ __launch_bounds__(256) void scatter_kernel(const int* __restrict__ rows,
                                                      const int* __restrict__ cols,
                                                      const float* __restrict__ f1,
                                                      const float* __restrict__ f2,
                                                      const int* __restrict__ rp,
                                                      int* __restrict__ cur,
                                                      int* __restrict__ ccol,
                                                      float* __restrict__ cval) {
    int e = blockIdx.x * 256 + threadIdx.x;
    if (e >= N_EDGES) return;
    int r = rows[e], c = cols[e];
    int pos = rp[r] + atomicAdd(&cur[r], 1);
    ccol[pos] = c;
    cval[pos] = __expf(f1[r] + f2[c]);
}

// per-row softmax normalize (one thread per row, CSR segment)
__global__ __launch_bounds__(256) void rownorm_kernel(const int* __restrict__ rp,
                                                      float* __restrict__ cval) {
    int r = blockIdx.x * 256 + threadIdx.x;
    if (r >= N_NODES) return;
    int a = rp[r], b = rp[r + 1];
    float s = 0.f;
    for (int j = a; j < b; ++j) s += cval[j];
    float inv = 1.f / s;
    for (int j = a; j < b; ++j) cval[j] *= inv;
}

// ---------------- fused SpMM: out = elu(0.2*A1@H + 0.8*A2@H) ----------------
// one wave per row; lane covers dims {lane, lane+64}
__global__ __launch_bounds__(256) void spmm_fused_kernel(const int* __restrict__ rp1,
                                                         const int* __restrict__ cc1,
                                                         const float* __restrict__ cv1,
                                                         const int* __restrict__ rp2,
                                                         const int* __restrict__ cc2,
                                                         const float* __restrict__ cv2,
                                                         const float* __restrict__ H,
                                                         float* __restrict__ out) {
    int r = blockIdx.x * 4 + (threadIdx.x >> 6);
    int lane = threadIdx.x & 63;
    float a0 = 0.f, a1 = 0.f;
    int e0 = rp1[r], e1 = rp1[r + 1];
    for (int j = e0; j < e1; ++j) {
        int c = cc1[j];
        float v = cv1[j];
        const float* h = H + (size_t)c * 128;
        a0 += v * h[lane];
        a1 += v * h[lane + 64];
    }
    float b0 = 0.f, b1 = 0.f;
    e0 = rp2[r]; e1 = rp2[r + 1];
    for (int j = e0; j < e1; ++j) {
        int c = cc2[j];
        float v = cv2[j];
        const float* h = H + (size_t)c * 128;
        b0 += v * h[lane];
        b1 += v * h[lane + 64];
    }
    float o0 = 0.2f * a0 + 0.8f * b0;
    float o1 = 0.2f * a1 + 0.8f * b1;
    o0 = o0 > 0.f ? o0 : expm1f(o0);
    o1 = o1 > 0.f ? o1 : expm1f(o1);
    out[(size_t)r * 128 + lane] = o0;
    out[(size_t)r * 128 + 64 + lane] = o1;
}

// ---------------- reductions -----------------------------------------------
__global__ __launch_bounds__(256) void sq_reduce_kernel(const float* __restrict__ a,
                                                        const float* __restrict__ b,
                                                        float* __restrict__ acc, int n) {
    __shared__ float sm[4];
    float s = 0.f;
    for (int i = blockIdx.x * 256 + threadIdx.x; i < n; i += gridDim.x * 256) {
        float d = b ? (a[i] - b[i]) : a[i];
        s += d * d;
    }
#pragma unroll
    for (int off = 32; off > 0; off >>= 1) s += __shfl_down(s, off);
    int lane = threadIdx.x & 63, w = threadIdx.x >> 6;
    if (lane == 0) sm[w] = s;
    __syncthreads();
    if (threadIdx.x == 0) {
        float t = sm[0] + sm[1] + sm[2] + sm[3];
        atomicAdd(acc, t);
    }
}

__global__ void finalize_kernel(const float* __restrict__ acc, float* __restrict__ out) {
    out[0] = sqrtf(acc[0]) + 1e-4f * (acc[1] + acc[2]);
}

extern "C" void kernel_launch(void* const* d_in, const int* in_sizes, int n_in,
                              void* d_out, int out_size, void* d_ws, size_t ws_size,
                              hipStream_t stream) {
    const float* X    = (const float*)d_in[0];
    const float* W0   = (const float*)d_in[1];
    const float* W1   = (const float*)d_in[2];
    const float* v00  = (const float*)d_in[3];
    const float* v01  = (const float*)d_in[4];
    const float* pv00 = (const float*)d_in[5];
    const float* pv01 = (const float*)d_in[6];
    const int* rows   = (const int*)d_in[7];
    const int* cols   = (const int*)d_in[8];
    const int* prows  = (const int*)d_in[9];
    const int* pcols  = (const int*)d_in[10];

    float* out  = (float*)d_out;
    float* Henc = out + 1;                                  // N x 64 (misaligned base)
    float* Xrec = out + 1 + (size_t)N_NODES * 64;           // N x 256 (misaligned base)

    // scratch carved out of the dead X_ region (fully overwritten at step 13)
    float* bufA = out + 6400004;                            // N x 128, 16B-aligned
    int*   cc1  = (int*)(out + 19200004);                   // E
    float* cv1  = out + 20800004;                           // E
    int*   cc2  = (int*)(out + 22400004);                   // E
    float* cv2  = out + 24000004;                           // E  (ends 25,600,004 < 32,000,001)

    float* ws   = (float*)d_ws;
    float* bufB = ws;                                       // N x 128
    float* f1   = bufB + (size_t)N_NODES * 128;
    float* f2   = f1 + N_NODES;
    float* pf1  = f2 + N_NODES;
    float* pf2  = pf1 + N_NODES;
    float* acc  = pf2 + N_NODES;                            // 4
    float* W1T  = acc + 4;                                  // 64 x 128
    float* W0T  = W1T + 64 * 128;                           // 128 x 256
    int*   rp1  = (int*)(W0T + 128 * 256);                  // N+1
    int*   rp2  = rp1 + N_NODES + 1;                        // N+1
    int*   deg1 = rp2 + N_NODES + 1;                        // N
    int*   cur1 = deg1 + N_NODES;                           // N
    int*   deg2 = cur1 + N_NODES;                           // N
    int*   cur2 = deg2 + N_NODES;                           // N
    int*   bsum = cur2 + N_NODES;                           // SCAN_NB

    const int n = N_NODES;
    const int EG = cdiv(N_EDGES, 256);

    // 0. weight transposes (tiny)
    transpose_kernel<<<cdiv(128 * 64, 256), 256, 0, stream>>>(W1, W1T, 128, 64);
    transpose_kernel<<<cdiv(256 * 128, 256), 256, 0, stream>>>(W0, W0T, 256, 128);

    // 1. H1 = X @ W0  -> bufA
    gemm_tiled<256, 128, true, true><<<n / 8, 256, 0, stream>>>(X, W0, bufA);

    // zero deg/cur (4N ints) + acc
    hipMemsetAsync(deg1, 0, 4 * (size_t)N_NODES * sizeof(int), stream);
    hipMemsetAsync(acc, 0, 4 * sizeof(float), stream);

    // 2. attention feature dots (all four in one pass over H1)
    attn_f4_kernel<<<cdiv(n, 4), 256, 0, stream>>>(bufA, v00, v01, pv00, pv01,
                                                   f1, f2, pf1, pf2);

    // 3. CSR build for both adjacencies
    hist_kernel<<<EG, 256, 0, stream>>>(rows, deg1);
    hist_kernel<<<EG, 256, 0, stream>>>(prows, deg2);
    scan1_kernel<<<SCAN_NB, 256, 0, stream>>>(deg1, bsum);
    scan2_kernel<<<1, 64, 0, stream>>>(bsum);
    scan3_kernel<<<SCAN_NB, 256, 0, stream>>>(deg1, bsum, rp1);
    scan1_kernel<<<SCAN_NB, 256, 0, stream>>>(deg2, bsum);
    scan2_kernel<<<1, 64, 0, stream>>>(bsum);
    scan3_kernel<<<SCAN_NB, 256, 0, stream>>>(deg2, bsum, rp2);
    scatter_kernel<<<EG, 256, 0, stream>>>(rows, cols, f1, f2, rp1, cur1, cc1, cv1);
    scatter_kernel<<<EG, 256, 0, stream>>>(prows, pcols, pf1, pf2, rp2, cur2, cc2, cv2);
    rownorm_kernel<<<cdiv(n, 256), 256, 0, stream>>>(rp1, cv1);
    rownorm_kernel<<<cdiv(n, 256), 256, 0, stream>>>(rp2, cv2);

    // 4. encoder: bufB = elu(0.2*A1@H1 + 0.8*A2@H1)
    spmm_fused_kernel<<<n / 4, 256, 0, stream>>>(rp1, cc1, cv1, rp2, cc2, cv2, bufA, bufB);

    // 5. Henc = bufB @ W1
    gemm_tiled<128, 64, true, false><<<n / 16, 256, 0, stream>>>(bufB, W1, Henc);

    // 6. D0 = Henc @ W1^T -> bufA
    gemm_tiled<64, 128, false, true><<<n / 8, 256, 0, stream>>>(Henc, W1T, bufA);

    // 7. decoder: bufB = elu(0.2*A1@D0 + 0.8*A2@D0)
    spmm_fused_kernel<<<n / 4, 256, 0, stream>>>(rp1, cc1, cv1, rp2, cc2, cv2, bufA, bufB);

    // 8. X_ = bufB @ W0^T -> Xrec (scratch in X_ region now dead)
    gemm_tiled<128, 256, true, false><<<n / 4, 256, 0, stream>>>(bufB, W0T, Xrec);

    // 9. loss
    sq_reduce_kernel<<<2048, 256, 0, stream>>>(X, Xrec, acc + 0, n * 256);
    sq_reduce_kernel<<<16, 256, 0, stream>>>(W0, nullptr, acc + 1, 256 * 128);
    sq_reduce_kernel<<<4, 256, 0, stream>>>(W1, nullptr, acc + 2, 128 * 64);
    finalize_kernel<<<1, 1, 0, stream>>>(acc, out);
}

// Round 4
// 1547.035 us; speedup vs baseline: 3.9841x; 1.0263x over previous
//
#include <hip/hip_runtime.h>
#include <math.h>

#define N_NODES 100000
#define N_EDGES 1600000
#define SCAN_NB 128   // blocks in scan kernels
#define SCAN_CH 4     // elements per thread in scan (128*256*4 = 131072 >= N+1)

static inline int cdiv(long a, long b) { return (int)((a + b - 1) / b); }

typedef unsigned int uint;
typedef unsigned short ushort;

__device__ inline float bf2f(uint u) { return __uint_as_float(u << 16); }
__device__ inline ushort f2bf(float f) {
    uint u = __float_as_uint(f);
    uint r = ((u >> 16) & 1u) + 0x7fffu;   // RNE
    return (ushort)((u + r) >> 16);
}

// ---------------- tiled GEMM: C[i,m] = sum_k A[i,k] * B[k,m], B row-major KxM
// OUT: 0 = fp32 scalar stores (unaligned base), 1 = fp32 float4, 2 = bf16 packed
// LOSS: fuse sum((C - Xref)^2) per block into partial[blockIdx.x] (M must be 256)
template <int K, int M, bool A4, int OUT, bool LOSS>
__global__ __launch_bounds__(256) void gemm_tiled(const float* __restrict__ A,
                                                  const float* __restrict__ B,
                                                  void* __restrict__ Cv,
                                                  const float* __restrict__ Xref,
                                                  float* __restrict__ partial) {
    constexpr int KC = 32;
    constexpr int R = 1024 / M;   // rows per block
    constexpr int TPR = M / 4;    // threads per row
    __shared__ float Blds[KC * M];
    const int trow = threadIdx.x / TPR;
    const int tcol = threadIdx.x % TPR;
    const int r = blockIdx.x * R + trow;
    float acc0 = 0.f, acc1 = 0.f, acc2 = 0.f, acc3 = 0.f;
    for (int k0 = 0; k0 < K; k0 += KC) {
        const float4* Bsrc = reinterpret_cast<const float4*>(B + (size_t)k0 * M);
        float4* Bdst = reinterpret_cast<float4*>(Blds);
#pragma unroll
        for (int i = 0; i < (KC * M / 4) / 256; ++i)
            Bdst[i * 256 + threadIdx.x] = Bsrc[i * 256 + threadIdx.x];
        __syncthreads();
        float a[KC];
        if (A4) {
            const float4* Asrc = reinterpret_cast<const float4*>(A + (size_t)r * K + k0);
#pragma unroll
            for (int i = 0; i < KC / 4; ++i) {
                float4 v = Asrc[i];
                a[4 * i] = v.x; a[4 * i + 1] = v.y; a[4 * i + 2] = v.z; a[4 * i + 3] = v.w;
            }
        } else {
#pragma unroll
            for (int i = 0; i < KC; ++i) a[i] = A[(size_t)r * K + k0 + i];
        }
#pragma unroll
        for (int kk = 0; kk < KC; ++kk) {
            const float* brow = Blds + kk * M + tcol * 4;
            acc0 += a[kk] * brow[0];
            acc1 += a[kk] * brow[1];
            acc2 += a[kk] * brow[2];
            acc3 += a[kk] * brow[3];
        }
        __syncthreads();
    }
    if (OUT == 0) {
        float* c = (float*)Cv + (size_t)r * M + tcol * 4;
        c[0] = acc0; c[1] = acc1; c[2] = acc2; c[3] = acc3;
    } else if (OUT == 1) {
        float* c = (float*)Cv + (size_t)r * M + tcol * 4;
        *reinterpret_cast<float4*>(c) = make_float4(acc0, acc1, acc2, acc3);
    } else {
        ushort* c = (ushort*)Cv + (size_t)r * M + tcol * 4;
        uint2 w;
        w.x = (uint)f2bf(acc0) | ((uint)f2bf(acc1) << 16);
        w.y = (uint)f2bf(acc2) | ((uint)f2bf(acc3) << 16);
        *reinterpret_cast<uint2*>(c) = w;
    }
    if (LOSS) {
        __shared__ float smRed[4];
        float4 xv = *reinterpret_cast<const float4*>(Xref + (size_t)r * 256 + tcol * 4);
        float d0 = acc0 - xv.x, d1 = acc1 - xv.y, d2 = acc2 - xv.z, d3 = acc3 - xv.w;
        float s = d0 * d0 + d1 * d1 + d2 * d2 + d3 * d3;
#pragma unroll
        for (int off = 32; off > 0; off >>= 1) s += __shfl_down(s, off);
        int lane = threadIdx.x & 63, w = threadIdx.x >> 6;
        if (lane == 0) smRed[w] = s;
        __syncthreads();
        if (threadIdx.x == 0)
            partial[blockIdx.x] = smRed[0] + smRed[1] + smRed[2] + smRed[3];
    }
}

// ---------------- small matrix transpose ------------------------------------
__global__ __launch_bounds__(256) void transpose_kernel(const float* __restrict__ in,
                                                        float* __restrict__ out,
                                                        int rows, int cols) {
    int i = blockIdx.x * 256 + threadIdx.x;
    if (i >= rows * cols) return;
    int r = i / cols, c = i - r * cols;
    out[c * rows + r] = in[i];
}

// ---------------- attention feature dots (bf16 H): all 4 at once ------------
__global__ __launch_bounds__(256) void attn_f4_kernel(const ushort* __restrict__ Hb,
                                                      const float* __restrict__ va,
                                                      const float* __restrict__ vb,
                                                      const float* __restrict__ pva,
                                                      const float* __restrict__ pvb,
                                                      float* __restrict__ f1,
                                                      float* __restrict__ f2,
                                                      float* __restrict__ pf1,
                                                      float* __restrict__ pf2) {
    int wid = (blockIdx.x * 256 + threadIdx.x) >> 6;  // one wave per row
    int lane = threadIdx.x & 63;
    if (wid >= N_NODES) return;
    uint hv = reinterpret_cast<const uint*>(Hb + (size_t)wid * 128)[lane];
    float x0 = bf2f(hv & 0xffffu);
    float x1 = bf2f(hv >> 16);
    int k = 2 * lane;
    float a = x0 * va[k] + x1 * va[k + 1];
    float b = x0 * vb[k] + x1 * vb[k + 1];
    float pa = x0 * pva[k] + x1 * pva[k + 1];
    float pb = x0 * pvb[k] + x1 * pvb[k + 1];
#pragma unroll
    for (int off = 32; off > 0; off >>= 1) {
        a += __shfl_down(a, off);
        b += __shfl_down(b, off);
        pa += __shfl_down(pa, off);
        pb += __shfl_down(pb, off);
    }
    if (lane == 0) { f1[wid] = a; f2[wid] = b; pf1[wid] = pa; pf2[wid] = pb; }
}

// ---------------- CSR build ------------------------------------------------
__global__ __launch_bounds__(256) void hist_kernel(const int* __restrict__ rows,
                                                   int* __restrict__ deg) {
    int e = blockIdx.x * 256 + threadIdx.x;
    if (e >= N_EDGES) return;
    atomicAdd(&deg[rows[e]], 1);
}

__global__ __launch_bounds__(256) void scan1_kernel(const int* __restrict__ deg,
                                                    int* __restrict__ bsum) {
    __shared__ int sm[256];
    int base = (blockIdx.x * 256 + threadIdx.x) * SCAN_CH;
    int s = 0;
#pragma unroll
    for (int i = 0; i < SCAN_CH; ++i) {
        int idx = base + i;
        if (idx < N_NODES) s += deg[idx];
    }
    sm[threadIdx.x] = s;
    __syncthreads();
    for (int off = 128; off > 0; off >>= 1) {
        if (threadIdx.x < off) sm[threadIdx.x] += sm[threadIdx.x + off];
        __syncthreads();
    }
    if (threadIdx.x == 0) bsum[blockIdx.x] = sm[0];
}

__global__ void scan2_kernel(int* __restrict__ bsum) {
    if (threadIdx.x != 0) return;
    int run = 0;
    for (int i = 0; i < SCAN_NB; ++i) {
        int t = bsum[i];
        bsum[i] = run;
        run += t;
    }
}

__global__ __launch_bounds__(256) void scan3_kernel(const int* __restrict__ deg,
                                                    const int* __restrict__ bsum,
                                                    int* __restrict__ rp) {
    __shared__ int sm[256];
    int base = (blockIdx.x * 256 + threadIdx.x) * SCAN_CH;
    int s = 0;
#pragma unroll
    for (int i = 0; i < SCAN_CH; ++i) {
        int idx = base + i;
        if (idx < N_NODES) s += deg[idx];
    }
    sm[threadIdx.x] = s;
    __syncthreads();
    if (threadIdx.x == 0) {
        int run = bsum[blockIdx.x];
        for (int t = 0; t < 256; ++t) { int tmp = sm[t]; sm[t] = run; run += tmp; }
    }
    __syncthreads();
    int off = sm[threadIdx.x];
#pragma unroll
    for (int i = 0; i < SCAN_CH; ++i) {
        int idx = base + i;
        if (idx < N_NODES) { rp[idx] = off; off += deg[idx]; }
        else if (idx == N_NODES) rp[idx] = off;
    }
}

__global__ __launch_bounds__(256) void scatter_kernel(const int* __restrict__ rows,
                                                      const int* __restrict__ cols,
                                                      const float* __restrict__ f1,
                                                      const float* __restrict__ f2,
                                                      const int* __restrict__ rp,
                                                      int* __restrict__ cur,
                                                      int* __restrict__ ccol,
                                                      float* __restrict__ cval) {
    int e = blockIdx.x * 256 + threadIdx.x;
    if (e >= N_EDGES) return;
    int r = rows[e], c = cols[e];
    int pos = rp[r] + atomicAdd(&cur[r], 1);
    ccol[pos] = c;
    cval[pos] = __expf(f1[r] + f2[c]);
}

__global__ __launch_bounds__(256) void rownorm_kernel(const int* __restrict__ rp,
                                                      float* __restrict__ cval) {
    int r = blockIdx.x * 256 + threadIdx.x;
    if (r >= N_NODES) return;
    int a = rp[r], b = rp[r + 1];
    float s = 0.f;
    for (int j = a; j < b; ++j) s += cval[j];
    float inv = 1.f / s;
    for (int j = a; j < b; ++j) cval[j] *= inv;
}

// ---------------- fused SpMM (bf16 gather): out = elu(0.2*A1@H + 0.8*A2@H) --
// one wave per row; lane covers dims {2*lane, 2*lane+1}
__global__ __launch_bounds__(256) void spmm_fused_kernel(const int* __restrict__ rp1,
                                                         const int* __restrict__ cc1,
                                                         const float* __restrict__ cv1,
                                                         const int* __restrict__ rp2,
                                                         const int* __restrict__ cc2,
                                                         const float* __restrict__ cv2,
                                                         const ushort* __restrict__ Hb,
                                                         float* __restrict__ out) {
    int r = blockIdx.x * 4 + (threadIdx.x >> 6);
    int lane = threadIdx.x & 63;
    float a0 = 0.f, a1 = 0.f;
    int e0 = rp1[r], e1 = rp1[r + 1];
    for (int j = e0; j < e1; ++j) {
        int c = cc1[j];
        float v = cv1[j];
        uint hv = reinterpret_cast<const uint*>(Hb + (size_t)c * 128)[lane];
        a0 += v * bf2f(hv & 0xffffu);
        a1 += v * bf2f(hv >> 16);
    }
    float b0 = 0.f, b1 = 0.f;
    e0 = rp2[r]; e1 = rp2[r + 1];
    for (int j = e0; j < e1; ++j) {
        int c = cc2[j];
        float v = cv2[j];
        uint hv = reinterpret_cast<const uint*>(Hb + (size_t)c * 128)[lane];
        b0 += v * bf2f(hv & 0xffffu);
        b1 += v * bf2f(hv >> 16);
    }
    float o0 = 0.2f * a0 + 0.8f * b0;
    float o1 = 0.2f * a1 + 0.8f * b1;
    o0 = o0 > 0.f ? o0 : expm1f(o0);
    o1 = o1 > 0.f ? o1 : expm1f(o1);
    *reinterpret_cast<float2*>(out + (size_t)r * 128 + 2 * lane) = make_float2(o0, o1);
}

// ---------------- reductions -----------------------------------------------
__global__ __launch_bounds__(256) void sq_reduce_kernel(const float* __restrict__ a,
                                                        float* __restrict__ acc, int n) {
    __shared__ float sm[4];
    float s = 0.f;
    for (int i = blockIdx.x * 256 + threadIdx.x; i < n; i += gridDim.x * 256) {
        float d = a[i];
        s += d * d;
    }
#pragma unroll
    for (int off = 32; off > 0; off >>= 1) s += __shfl_down(s, off);
    int lane = threadIdx.x & 63, w = threadIdx.x >> 6;
    if (lane == 0) sm[w] = s;
    __syncthreads();
    if (threadIdx.x == 0) atomicAdd(acc, sm[0] + sm[1] + sm[2] + sm[3]);
}

__global__ __launch_bounds__(256) void partial_reduce_kernel(const float* __restrict__ p,
                                                             int n, float* __restrict__ acc) {
    __shared__ float sm[4];
    float s = 0.f;
    for (int i = threadIdx.x; i < n; i += 256) s += p[i];
#pragma unroll
    for (int off = 32; off > 0; off >>= 1) s += __shfl_down(s, off);
    int lane = threadIdx.x & 63, w = threadIdx.x >> 6;
    if (lane == 0) sm[w] = s;
    __syncthreads();
    if (threadIdx.x == 0) atomicAdd(acc, sm[0] + sm[1] + sm[2] + sm[3]);
}

__global__ void finalize_kernel(const float* __restrict__ acc, float* __restrict__ out) {
    out[0] = sqrtf(acc[0]) + 1e-4f * (acc[1] + acc[2]);
}

extern "C" void kernel_launch(void* const* d_in, const int* in_sizes, int n_in,
                              void* d_out, int out_size, void* d_ws, size_t ws_size,
                              hipStream_t stream) {
    const float* X    = (const float*)d_in[0];
    const float* W0   = (const float*)d_in[1];
    const float* W1   = (const float*)d_in[2];
    const float* v00  = (const float*)d_in[3];
    const float* v01  = (const float*)d_in[4];
    const float* pv00 = (const float*)d_in[5];
    const float* pv01 = (const float*)d_in[6];
    const int* rows   = (const int*)d_in[7];
    const int* cols   = (const int*)d_in[8];
    const int* prows  = (const int*)d_in[9];
    const int* pcols  = (const int*)d_in[10];

    float* out  = (float*)d_out;
    float* Henc = out + 1;                                  // N x 64 (misaligned base)
    float* Xrec = out + 1 + (size_t)N_NODES * 64;           // N x 256 (misaligned base)

    // scratch carved out of the dead X_ region (fully overwritten at step 8)
    ushort* bufAh = (ushort*)(out + 6400004);               // N x 128 bf16 (16B-aligned)
    int*   cc1  = (int*)(out + 19200004);                   // E
    float* cv1  = out + 20800004;                           // E
    int*   cc2  = (int*)(out + 22400004);                   // E
    float* cv2  = out + 24000004;                           // E

    float* ws   = (float*)d_ws;
    float* bufB = ws;                                       // N x 128 fp32
    float* f1   = bufB + (size_t)N_NODES * 128;
    float* f2   = f1 + N_NODES;
    float* pf1  = f2 + N_NODES;
    float* pf2  = pf1 + N_NODES;
    float* acc  = pf2 + N_NODES;                            // 4
    float* W1T  = acc + 4;                                  // 64 x 128
    float* W0T  = W1T + 64 * 128;                           // 128 x 256
    int*   rp1  = (int*)(W0T + 128 * 256);                  // N+1
    int*   rp2  = rp1 + N_NODES + 1;                        // N+1
    int*   deg1 = rp2 + N_NODES + 1;                        // N
    int*   cur1 = deg1 + N_NODES;                           // N
    int*   deg2 = cur1 + N_NODES;                           // N
    int*   cur2 = deg2 + N_NODES;                           // N
    int*   bsum = cur2 + N_NODES;                           // SCAN_NB
    float* partial = (float*)(bsum + SCAN_NB);              // n/4 floats

    const int n = N_NODES;
    const int EG = cdiv(N_EDGES, 256);

    // 0. weight transposes (tiny)
    transpose_kernel<<<cdiv(128 * 64, 256), 256, 0, stream>>>(W1, W1T, 128, 64);
    transpose_kernel<<<cdiv(256 * 128, 256), 256, 0, stream>>>(W0, W0T, 256, 128);

    // 1. H1 = X @ W0 -> bufAh (bf16)
    gemm_tiled<256, 128, true, 2, false><<<n / 8, 256, 0, stream>>>(X, W0, bufAh, nullptr, nullptr);

    // zero deg/cur (4N ints) + acc
    hipMemsetAsync(deg1, 0, 4 * (size_t)N_NODES * sizeof(int), stream);
    hipMemsetAsync(acc, 0, 4 * sizeof(float), stream);

    // 2. attention feature dots (one pass over bf16 H1)
    attn_f4_kernel<<<cdiv(n, 4), 256, 0, stream>>>(bufAh, v00, v01, pv00, pv01,
                                                   f1, f2, pf1, pf2);

    // 3. CSR build for both adjacencies
    hist_kernel<<<EG, 256, 0, stream>>>(rows, deg1);
    hist_kernel<<<EG, 256, 0, stream>>>(prows, deg2);
    scan1_kernel<<<SCAN_NB, 256, 0, stream>>>(deg1, bsum);
    scan2_kernel<<<1, 64, 0, stream>>>(bsum);
    scan3_kernel<<<SCAN_NB, 256, 0, stream>>>(deg1, bsum, rp1);
    scan1_kernel<<<SCAN_NB, 256, 0, stream>>>(deg2, bsum);
    scan2_kernel<<<1, 64, 0, stream>>>(bsum);
    scan3_kernel<<<SCAN_NB, 256, 0, stream>>>(deg2, bsum, rp2);
    scatter_kernel<<<EG, 256, 0, stream>>>(rows, cols, f1, f2, rp1, cur1, cc1, cv1);
    scatter_kernel<<<EG, 256, 0, stream>>>(prows, pcols, pf1, pf2, rp2, cur2, cc2, cv2);
    rownorm_kernel<<<cdiv(n, 256), 256, 0, stream>>>(rp1, cv1);
    rownorm_kernel<<<cdiv(n, 256), 256, 0, stream>>>(rp2, cv2);

    // 4. encoder: bufB = elu(0.2*A1@H1 + 0.8*A2@H1)  (bf16 gather)
    spmm_fused_kernel<<<n / 4, 256, 0, stream>>>(rp1, cc1, cv1, rp2, cc2, cv2, bufAh, bufB);

    // 5. Henc = bufB @ W1 -> d_out
    gemm_tiled<128, 64, true, 0, false><<<n / 16, 256, 0, stream>>>(bufB, W1, Henc, nullptr, nullptr);

    // 6. D0 = Henc @ W1^T -> bufAh (bf16)
    gemm_tiled<64, 128, false, 2, false><<<n / 8, 256, 0, stream>>>(Henc, W1T, bufAh, nullptr, nullptr);

    // 7. decoder: bufB = elu(0.2*A1@D0 + 0.8*A2@D0)  (bf16 gather)
    spmm_fused_kernel<<<n / 4, 256, 0, stream>>>(rp1, cc1, cv1, rp2, cc2, cv2, bufAh, bufB);

    // 8. X_ = bufB @ W0^T -> Xrec, fused sum((X - X_)^2) -> partial
    gemm_tiled<128, 256, true, 0, true><<<n / 4, 256, 0, stream>>>(bufB, W0T, Xrec, X, partial);

    // 9. loss
    partial_reduce_kernel<<<1, 256, 0, stream>>>(partial, n / 4, acc + 0);
    sq_reduce_kernel<<<16, 256, 0, stream>>>(W0, acc + 1, 256 * 128);
    sq_reduce_kernel<<<4, 256, 0, stream>>>(W1, acc + 2, 128 * 64);
    finalize_kernel<<<1, 1, 0, stream>>>(acc, out);
}

// Round 5
// 1340.341 us; speedup vs baseline: 4.5984x; 1.1542x over previous
//
#include <hip/hip_runtime.h>
#include <math.h>

#define N_NODES 100000
#define N_EDGES 1600000
#define SCAN_NB 128   // blocks in scan kernels
#define SCAN_CH 4     // elements per thread in scan (128*256*4 = 131072 >= N+1)

static inline int cdiv(long a, long b) { return (int)((a + b - 1) / b); }

typedef unsigned int uint;
typedef unsigned short ushort;

__device__ inline float bf2f(uint u) { return __uint_as_float(u << 16); }
__device__ inline ushort f2bf(float f) {
    uint u = __float_as_uint(f);
    uint r = ((u >> 16) & 1u) + 0x7fffu;   // RNE
    return (ushort)((u + r) >> 16);
}

// ---------------- tiled GEMM: C[i,m] = sum_k A[i,k] * B[k,m], B row-major KxM
// OUT: 0 = fp32 scalar stores (unaligned base), 1 = fp32 float4, 2 = bf16 packed
// LOSS: fuse sum((C - Xref)^2) per block into partial[blockIdx.x] (M must be 256)
template <int K, int M, bool A4, int OUT, bool LOSS>
__global__ __launch_bounds__(256) void gemm_tiled(const float* __restrict__ A,
                                                  const float* __restrict__ B,
                                                  void* __restrict__ Cv,
                                                  const float* __restrict__ Xref,
                                                  float* __restrict__ partial) {
    constexpr int KC = 32;
    constexpr int R = 1024 / M;   // rows per block
    constexpr int TPR = M / 4;    // threads per row
    __shared__ float Blds[KC * M];
    const int trow = threadIdx.x / TPR;
    const int tcol = threadIdx.x % TPR;
    const int r = blockIdx.x * R + trow;
    float acc0 = 0.f, acc1 = 0.f, acc2 = 0.f, acc3 = 0.f;
    for (int k0 = 0; k0 < K; k0 += KC) {
        const float4* Bsrc = reinterpret_cast<const float4*>(B + (size_t)k0 * M);
        float4* Bdst = reinterpret_cast<float4*>(Blds);
#pragma unroll
        for (int i = 0; i < (KC * M / 4) / 256; ++i)
            Bdst[i * 256 + threadIdx.x] = Bsrc[i * 256 + threadIdx.x];
        __syncthreads();
        float a[KC];
        if (A4) {
            const float4* Asrc = reinterpret_cast<const float4*>(A + (size_t)r * K + k0);
#pragma unroll
            for (int i = 0; i < KC / 4; ++i) {
                float4 v = Asrc[i];
                a[4 * i] = v.x; a[4 * i + 1] = v.y; a[4 * i + 2] = v.z; a[4 * i + 3] = v.w;
            }
        } else {
#pragma unroll
            for (int i = 0; i < KC; ++i) a[i] = A[(size_t)r * K + k0 + i];
        }
#pragma unroll
        for (int kk = 0; kk < KC; ++kk) {
            const float* brow = Blds + kk * M + tcol * 4;
            acc0 += a[kk] * brow[0];
            acc1 += a[kk] * brow[1];
            acc2 += a[kk] * brow[2];
            acc3 += a[kk] * brow[3];
        }
        __syncthreads();
    }
    if (OUT == 0) {
        float* c = (float*)Cv + (size_t)r * M + tcol * 4;
        c[0] = acc0; c[1] = acc1; c[2] = acc2; c[3] = acc3;
    } else if (OUT == 1) {
        float* c = (float*)Cv + (size_t)r * M + tcol * 4;
        *reinterpret_cast<float4*>(c) = make_float4(acc0, acc1, acc2, acc3);
    } else {
        ushort* c = (ushort*)Cv + (size_t)r * M + tcol * 4;
        uint2 w;
        w.x = (uint)f2bf(acc0) | ((uint)f2bf(acc1) << 16);
        w.y = (uint)f2bf(acc2) | ((uint)f2bf(acc3) << 16);
        *reinterpret_cast<uint2*>(c) = w;
    }
    if (LOSS) {
        __shared__ float smRed[4];
        float4 xv = *reinterpret_cast<const float4*>(Xref + (size_t)r * 256 + tcol * 4);
        float d0 = acc0 - xv.x, d1 = acc1 - xv.y, d2 = acc2 - xv.z, d3 = acc3 - xv.w;
        float s = d0 * d0 + d1 * d1 + d2 * d2 + d3 * d3;
#pragma unroll
        for (int off = 32; off > 0; off >>= 1) s += __shfl_down(s, off);
        int lane = threadIdx.x & 63, w = threadIdx.x >> 6;
        if (lane == 0) smRed[w] = s;
        __syncthreads();
        if (threadIdx.x == 0)
            partial[blockIdx.x] = smRed[0] + smRed[1] + smRed[2] + smRed[3];
    }
}

// ---------------- small matrix transpose ------------------------------------
__global__ __launch_bounds__(256) void transpose_kernel(const float* __restrict__ in,
                                                        float* __restrict__ out,
                                                        int rows, int cols) {
    int i = blockIdx.x * 256 + threadIdx.x;
    if (i >= rows * cols) return;
    int r = i / cols, c = i - r * cols;
    out[c * rows + r] = in[i];
}

// ---------------- attention feature dots (bf16 H): all 4 at once ------------
__global__ __launch_bounds__(256) void attn_f4_kernel(const ushort* __restrict__ Hb,
                                                      const float* __restrict__ va,
                                                      const float* __restrict__ vb,
                                                      const float* __restrict__ pva,
                                                      const float* __restrict__ pvb,
                                                      float* __restrict__ f1,
                                                      float* __restrict__ f2,
                                                      float* __restrict__ pf1,
                                                      float* __restrict__ pf2) {
    int wid = (blockIdx.x * 256 + threadIdx.x) >> 6;  // one wave per row
    int lane = threadIdx.x & 63;
    if (wid >= N_NODES) return;
    uint hv = reinterpret_cast<const uint*>(Hb + (size_t)wid * 128)[lane];
    float x0 = bf2f(hv & 0xffffu);
    float x1 = bf2f(hv >> 16);
    int k = 2 * lane;
    float a = x0 * va[k] + x1 * va[k + 1];
    float b = x0 * vb[k] + x1 * vb[k + 1];
    float pa = x0 * pva[k] + x1 * pva[k + 1];
    float pb = x0 * pvb[k] + x1 * pvb[k + 1];
#pragma unroll
    for (int off = 32; off > 0; off >>= 1) {
        a += __shfl_down(a, off);
        b += __shfl_down(b, off);
        pa += __shfl_down(pa, off);
        pb += __shfl_down(pb, off);
    }
    if (lane == 0) { f1[wid] = a; f2[wid] = b; pf1[wid] = pa; pf2[wid] = pb; }
}

// ---------------- CSR build ------------------------------------------------
__global__ __launch_bounds__(256) void hist_kernel(const int* __restrict__ rows,
                                                   int* __restrict__ deg) {
    int e = blockIdx.x * 256 + threadIdx.x;
    if (e >= N_EDGES) return;
    atomicAdd(&deg[rows[e]], 1);
}

__global__ __launch_bounds__(256) void scan1_kernel(const int* __restrict__ deg,
                                                    int* __restrict__ bsum) {
    __shared__ int sm[256];
    int base = (blockIdx.x * 256 + threadIdx.x) * SCAN_CH;
    int s = 0;
#pragma unroll
    for (int i = 0; i < SCAN_CH; ++i) {
        int idx = base + i;
        if (idx < N_NODES) s += deg[idx];
    }
    sm[threadIdx.x] = s;
    __syncthreads();
    for (int off = 128; off > 0; off >>= 1) {
        if (threadIdx.x < off) sm[threadIdx.x] += sm[threadIdx.x + off];
        __syncthreads();
    }
    if (threadIdx.x == 0) bsum[blockIdx.x] = sm[0];
}

__global__ void scan2_kernel(int* __restrict__ bsum) {
    if (threadIdx.x != 0) return;
    int run = 0;
    for (int i = 0; i < SCAN_NB; ++i) {
        int t = bsum[i];
        bsum[i] = run;
        run += t;
    }
}

__global__ __launch_bounds__(256) void scan3_kernel(const int* __restrict__ deg,
                                                    const int* __restrict__ bsum,
                                                    int* __restrict__ rp) {
    __shared__ int sm[256];
    int base = (blockIdx.x * 256 + threadIdx.x) * SCAN_CH;
    int s = 0;
#pragma unroll
    for (int i = 0; i < SCAN_CH; ++i) {
        int idx = base + i;
        if (idx < N_NODES) s += deg[idx];
    }
    sm[threadIdx.x] = s;
    __syncthreads();
    if (threadIdx.x == 0) {
        int run = bsum[blockIdx.x];
        for (int t = 0; t < 256; ++t) { int tmp = sm[t]; sm[t] = run; run += tmp; }
    }
    __syncthreads();
    int off = sm[threadIdx.x];
#pragma unroll
    for (int i = 0; i < SCAN_CH; ++i) {
        int idx = base + i;
        if (idx < N_NODES) { rp[idx] = off; off += deg[idx]; }
        else if (idx == N_NODES) rp[idx] = off;
    }
}

// scatter edges into CSR slots (packed {col, exp}) + accumulate row sums
__global__ __launch_bounds__(256) void scatter_kernel(const int* __restrict__ rows,
                                                      const int* __restrict__ cols,
                                                      const float* __restrict__ f1,
                                                      const float* __restrict__ f2,
                                                      const int* __restrict__ rp,
                                                      int* __restrict__ cur,
                                                      int2* __restrict__ edg,
                                                      float* __restrict__ s) {
    int e = blockIdx.x * 256 + threadIdx.x;
    if (e >= N_EDGES) return;
    int r = rows[e], c = cols[e];
    float v = __expf(f1[r] + f2[c]);
    int pos = rp[r] + atomicAdd(&cur[r], 1);
    edg[pos] = make_int2(c, __float_as_int(v));
    atomicAdd(&s[r], v);
}

// ---------------- fused SpMM (bf16 gather, unroll-8, both adjacencies) ------
// out = elu(0.2*(A1@H)/s1 + 0.8*(A2@H)/s2); one wave per row, 2 dims/lane
#define SPU 8
__device__ inline void gather_block(const int2* __restrict__ eg, int j,
                                    const uint* __restrict__ Hu, int lane,
                                    float& s0, float& s1) {
    int2 d[SPU];
#pragma unroll
    for (int u = 0; u < SPU; ++u) d[u] = eg[j + u];
    uint h[SPU];
#pragma unroll
    for (int u = 0; u < SPU; ++u) h[u] = Hu[(size_t)d[u].x * 64 + lane];
#pragma unroll
    for (int u = 0; u < SPU; ++u) {
        float v = __int_as_float(d[u].y);
        s0 += v * bf2f(h[u] & 0xffffu);
        s1 += v * bf2f(h[u] >> 16);
    }
}

__global__ __launch_bounds__(256) void spmm_fused_kernel(const int* __restrict__ rp1,
                                                         const int2* __restrict__ eg1,
                                                         const float* __restrict__ s1a,
                                                         const int* __restrict__ rp2,
                                                         const int2* __restrict__ eg2,
                                                         const float* __restrict__ s2a,
                                                         const ushort* __restrict__ Hb,
                                                         float* __restrict__ out) {
    int r = blockIdx.x * 4 + (threadIdx.x >> 6);
    int lane = threadIdx.x & 63;
    const uint* Hu = reinterpret_cast<const uint*>(Hb);
    float a0 = 0.f, a1 = 0.f, b0 = 0.f, b1 = 0.f;
    int j1 = rp1[r], E1 = rp1[r + 1];
    int j2 = rp2[r], E2 = rp2[r + 1];
    // combined main loop: 16 descriptor loads, then 16 gathers in flight
    while (j1 + SPU <= E1 && j2 + SPU <= E2) {
        int2 d1[SPU], d2[SPU];
#pragma unroll
        for (int u = 0; u < SPU; ++u) d1[u] = eg1[j1 + u];
#pragma unroll
        for (int u = 0; u < SPU; ++u) d2[u] = eg2[j2 + u];
        uint h1[SPU], h2[SPU];
#pragma unroll
        for (int u = 0; u < SPU; ++u) h1[u] = Hu[(size_t)d1[u].x * 64 + lane];
#pragma unroll
        for (int u = 0; u < SPU; ++u) h2[u] = Hu[(size_t)d2[u].x * 64 + lane];
#pragma unroll
        for (int u = 0; u < SPU; ++u) {
            float v1 = __int_as_float(d1[u].y);
            float v2 = __int_as_float(d2[u].y);
            a0 += v1 * bf2f(h1[u] & 0xffffu);
            a1 += v1 * bf2f(h1[u] >> 16);
            b0 += v2 * bf2f(h2[u] & 0xffffu);
            b1 += v2 * bf2f(h2[u] >> 16);
        }
        j1 += SPU; j2 += SPU;
    }
    while (j1 + SPU <= E1) { gather_block(eg1, j1, Hu, lane, a0, a1); j1 += SPU; }
    while (j2 + SPU <= E2) { gather_block(eg2, j2, Hu, lane, b0, b1); j2 += SPU; }
    for (; j1 < E1; ++j1) {
        int2 d = eg1[j1];
        uint h = Hu[(size_t)d.x * 64 + lane];
        float v = __int_as_float(d.y);
        a0 += v * bf2f(h & 0xffffu);
        a1 += v * bf2f(h >> 16);
    }
    for (; j2 < E2; ++j2) {
        int2 d = eg2[j2];
        uint h = Hu[(size_t)d.x * 64 + lane];
        float v = __int_as_float(d.y);
        b0 += v * bf2f(h & 0xffffu);
        b1 += v * bf2f(h >> 16);
    }
    float s1 = s1a[r], s2 = s2a[r];
    float w1 = s1 > 0.f ? 0.2f / s1 : 0.f;
    float w2 = s2 > 0.f ? 0.8f / s2 : 0.f;
    float o0 = w1 * a0 + w2 * b0;
    float o1 = w1 * a1 + w2 * b1;
    o0 = o0 > 0.f ? o0 : expm1f(o0);
    o1 = o1 > 0.f ? o1 : expm1f(o1);
    *reinterpret_cast<float2*>(out + (size_t)r * 128 + 2 * lane) = make_float2(o0, o1);
}

// ---------------- reductions -----------------------------------------------
__global__ __launch_bounds__(256) void sq_reduce_kernel(const float* __restrict__ a,
                                                        float* __restrict__ acc, int n) {
    __shared__ float sm[4];
    float s = 0.f;
    for (int i = blockIdx.x * 256 + threadIdx.x; i < n; i += gridDim.x * 256) {
        float d = a[i];
        s += d * d;
    }
#pragma unroll
    for (int off = 32; off > 0; off >>= 1) s += __shfl_down(s, off);
    int lane = threadIdx.x & 63, w = threadIdx.x >> 6;
    if (lane == 0) sm[w] = s;
    __syncthreads();
    if (threadIdx.x == 0) atomicAdd(acc, sm[0] + sm[1] + sm[2] + sm[3]);
}

__global__ __launch_bounds__(256) void partial_reduce_kernel(const float* __restrict__ p,
                                                             int n, float* __restrict__ acc) {
    __shared__ float sm[4];
    float s = 0.f;
    for (int i = threadIdx.x; i < n; i += 256) s += p[i];
#pragma unroll
    for (int off = 32; off > 0; off >>= 1) s += __shfl_down(s, off);
    int lane = threadIdx.x & 63, w = threadIdx.x >> 6;
    if (lane == 0) sm[w] = s;
    __syncthreads();
    if (threadIdx.x == 0) atomicAdd(acc, sm[0] + sm[1] + sm[2] + sm[3]);
}

__global__ void finalize_kernel(const float* __restrict__ acc, float* __restrict__ out) {
    out[0] = sqrtf(acc[0]) + 1e-4f * (acc[1] + acc[2]);
}

extern "C" void kernel_launch(void* const* d_in, const int* in_sizes, int n_in,
                              void* d_out, int out_size, void* d_ws, size_t ws_size,
                              hipStream_t stream) {
    const float* X    = (const float*)d_in[0];
    const float* W0   = (const float*)d_in[1];
    const float* W1   = (const float*)d_in[2];
    const float* v00  = (const float*)d_in[3];
    const float* v01  = (const float*)d_in[4];
    const float* pv00 = (const float*)d_in[5];
    const float* pv01 = (const float*)d_in[6];
    const int* rows   = (const int*)d_in[7];
    const int* cols   = (const int*)d_in[8];
    const int* prows  = (const int*)d_in[9];
    const int* pcols  = (const int*)d_in[10];

    float* out  = (float*)d_out;
    float* Henc = out + 1;                                  // N x 64 (misaligned base)
    float* Xrec = out + 1 + (size_t)N_NODES * 64;           // N x 256 (misaligned base)

    // scratch carved out of the dead X_ region (fully overwritten at step 8)
    ushort* bufAh = (ushort*)(out + 6400004);               // N x 128 bf16
    int2*  eg1  = (int2*)(out + 12800004);                  // E packed {col, exp}
    int2*  eg2  = (int2*)(out + 16000004);                  // E

    float* ws   = (float*)d_ws;
    float* bufB = ws;                                       // N x 128 fp32
    float* f1   = bufB + (size_t)N_NODES * 128;
    float* f2   = f1 + N_NODES;
    float* pf1  = f2 + N_NODES;
    float* pf2  = pf1 + N_NODES;
    float* s1   = pf2 + N_NODES;                            // N (raw exp row sums)
    float* s2   = s1 + N_NODES;                             // N
    float* acc  = s2 + N_NODES;                             // 4
    float* W1T  = acc + 4;                                  // 64 x 128
    float* W0T  = W1T + 64 * 128;                           // 128 x 256
    int*   rp1  = (int*)(W0T + 128 * 256);                  // N+1
    int*   rp2  = rp1 + N_NODES + 1;                        // N+1
    int*   deg1 = rp2 + N_NODES + 1;                        // N
    int*   cur1 = deg1 + N_NODES;                           // N
    int*   deg2 = cur1 + N_NODES;                           // N
    int*   cur2 = deg2 + N_NODES;                           // N
    int*   bsum = cur2 + N_NODES;                           // SCAN_NB
    float* partial = (float*)(bsum + SCAN_NB);              // n/4 floats

    const int n = N_NODES;
    const int EG = cdiv(N_EDGES, 256);

    // 0. weight transposes (tiny)
    transpose_kernel<<<cdiv(128 * 64, 256), 256, 0, stream>>>(W1, W1T, 128, 64);
    transpose_kernel<<<cdiv(256 * 128, 256), 256, 0, stream>>>(W0, W0T, 256, 128);

    // 1. H1 = X @ W0 -> bufAh (bf16)
    gemm_tiled<256, 128, true, 2, false><<<n / 8, 256, 0, stream>>>(X, W0, bufAh, nullptr, nullptr);

    // zero deg/cur (4N ints), s1/s2 (2N floats), acc
    hipMemsetAsync(deg1, 0, 4 * (size_t)N_NODES * sizeof(int), stream);
    hipMemsetAsync(s1, 0, (2 * (size_t)N_NODES + 4) * sizeof(float), stream);

    // 2. attention feature dots (one pass over bf16 H1)
    attn_f4_kernel<<<cdiv(n, 4), 256, 0, stream>>>(bufAh, v00, v01, pv00, pv01,
                                                   f1, f2, pf1, pf2);

    // 3. CSR build for both adjacencies (+ raw exp row sums)
    hist_kernel<<<EG, 256, 0, stream>>>(rows, deg1);
    hist_kernel<<<EG, 256, 0, stream>>>(prows, deg2);
    scan1_kernel<<<SCAN_NB, 256, 0, stream>>>(deg1, bsum);
    scan2_kernel<<<1, 64, 0, stream>>>(bsum);
    scan3_kernel<<<SCAN_NB, 256, 0, stream>>>(deg1, bsum, rp1);
    scan1_kernel<<<SCAN_NB, 256, 0, stream>>>(deg2, bsum);
    scan2_kernel<<<1, 64, 0, stream>>>(bsum);
    scan3_kernel<<<SCAN_NB, 256, 0, stream>>>(deg2, bsum, rp2);
    scatter_kernel<<<EG, 256, 0, stream>>>(rows, cols, f1, f2, rp1, cur1, eg1, s1);
    scatter_kernel<<<EG, 256, 0, stream>>>(prows, pcols, pf1, pf2, rp2, cur2, eg2, s2);

    // 4. encoder: bufB = elu(0.2*(A1@H1)/s1 + 0.8*(A2@H1)/s2)
    spmm_fused_kernel<<<n / 4, 256, 0, stream>>>(rp1, eg1, s1, rp2, eg2, s2, bufAh, bufB);

    // 5. Henc = bufB @ W1 -> d_out
    gemm_tiled<128, 64, true, 0, false><<<n / 16, 256, 0, stream>>>(bufB, W1, Henc, nullptr, nullptr);

    // 6. D0 = Henc @ W1^T -> bufAh (bf16)
    gemm_tiled<64, 128, false, 2, false><<<n / 8, 256, 0, stream>>>(Henc, W1T, bufAh, nullptr, nullptr);

    // 7. decoder: bufB = elu(0.2*(A1@D0)/s1 + 0.8*(A2@D0)/s2)
    spmm_fused_kernel<<<n / 4, 256, 0, stream>>>(rp1, eg1, s1, rp2, eg2, s2, bufAh, bufB);

    // 8. X_ = bufB @ W0^T -> Xrec, fused sum((X - X_)^2) -> partial
    gemm_tiled<128, 256, true, 0, true><<<n / 4, 256, 0, stream>>>(bufB, W0T, Xrec, X, partial);

    // 9. loss
    partial_reduce_kernel<<<1, 256, 0, stream>>>(partial, n / 4, acc + 0);
    sq_reduce_kernel<<<16, 256, 0, stream>>>(W0, acc + 1, 256 * 128);
    sq_reduce_kernel<<<4, 256, 0, stream>>>(W1, acc + 2, 128 * 64);
    finalize_kernel<<<1, 1, 0, stream>>>(acc, out);
}

// Round 6
// 1159.566 us; speedup vs baseline: 5.3153x; 1.1559x over previous
//
#include <hip/hip_runtime.h>
#include <math.h>

#define N_NODES 100000
#define N_EDGES 1600000
#define SCAN_NB 128   // blocks in scan kernels
#define SCAN_CH 4     // elements per thread in scan (128*256*4 = 131072 >= N+1)

static inline int cdiv(long a, long b) { return (int)((a + b - 1) / b); }

typedef unsigned int uint;
typedef unsigned short ushort;

__device__ inline float bf2f(uint u) { return __uint_as_float(u << 16); }
__device__ inline ushort f2bf(float f) {
    uint u = __float_as_uint(f);
    uint r = ((u >> 16) & 1u) + 0x7fffu;   // RNE
    return (ushort)((u + r) >> 16);
}

// ------------- register-blocked GEMM: C[i,m] = sum_k A[i,k]*B[k,m] ----------
// B row-major KxM. Block = 256 threads; tile = R rows x M cols; each thread
// computes 4 rows x 4 cols (16 FMA per 2 ds_read_b128; A-frag is wave-broadcast).
// OUT: 0 = fp32 scalar stores (unaligned base), 2 = bf16 packed
// LOSS: fuse sum((C-Xref)^2) per block into partial[blockIdx.x] (needs M==256)
// GUARD: R does not divide nrows -> clamp loads, guard stores
template <int K, int M, int R, int OUT, bool LOSS, bool GUARD>
__global__ __launch_bounds__(256) void gemm_rb(const float* __restrict__ A,
                                               const float* __restrict__ B,
                                               void* __restrict__ Cv,
                                               const float* __restrict__ Xref,
                                               float* __restrict__ partial,
                                               int nrows) {
    constexpr int KC = 32;
    constexpr int TPR = M / 4;        // threads spanning M
    constexpr int G = 256 / TPR;      // row-groups of 4 rows
    static_assert(G * 4 == R, "tile geometry");
    __shared__ float Blds[KC * M];
    __shared__ float Alds[KC][R];
    const int tcol = threadIdx.x % TPR;
    const int tg   = threadIdx.x / TPR;
    const int rbase = blockIdx.x * R;
    float acc[4][4] = {};
    for (int k0 = 0; k0 < K; k0 += KC) {
        const float4* Bsrc = reinterpret_cast<const float4*>(B + (size_t)k0 * M);
        float4* Bdst = reinterpret_cast<float4*>(Blds);
#pragma unroll
        for (int i = 0; i < (KC * M / 4) / 256; ++i)
            Bdst[i * 256 + threadIdx.x] = Bsrc[i * 256 + threadIdx.x];
        // A chunk R x KC, stored transposed Alds[k][r]
#pragma unroll
        for (int e = threadIdx.x; e < R * KC; e += 256) {
            int rr = e / KC, kk = e - rr * KC;
            int rg = rbase + rr;
            if (GUARD) rg = min(rg, nrows - 1);
            Alds[kk][rr] = A[(size_t)rg * K + k0 + kk];
        }
        __syncthreads();
#pragma unroll
        for (int kk = 0; kk < KC; ++kk) {
            float4 av = *reinterpret_cast<const float4*>(&Alds[kk][tg * 4]);
            float4 bv = *reinterpret_cast<const float4*>(&Blds[kk * M + tcol * 4]);
            float ar[4] = {av.x, av.y, av.z, av.w};
            float br[4] = {bv.x, bv.y, bv.z, bv.w};
#pragma unroll
            for (int i = 0; i < 4; ++i)
#pragma unroll
                for (int j = 0; j < 4; ++j)
                    acc[i][j] += ar[i] * br[j];
        }
        __syncthreads();
    }
    float lsum = 0.f;
#pragma unroll
    for (int i = 0; i < 4; ++i) {
        int r = rbase + tg * 4 + i;
        if (GUARD && r >= nrows) continue;
        if (OUT == 0) {
            float* c = (float*)Cv + (size_t)r * M + tcol * 4;
            c[0] = acc[i][0]; c[1] = acc[i][1]; c[2] = acc[i][2]; c[3] = acc[i][3];
        } else {
            ushort* c = (ushort*)Cv + (size_t)r * M + tcol * 4;
            uint2 w;
            w.x = (uint)f2bf(acc[i][0]) | ((uint)f2bf(acc[i][1]) << 16);
            w.y = (uint)f2bf(acc[i][2]) | ((uint)f2bf(acc[i][3]) << 16);
            *reinterpret_cast<uint2*>(c) = w;
        }
        if (LOSS) {
            float4 xv = *reinterpret_cast<const float4*>(Xref + (size_t)r * 256 + tcol * 4);
            float d0 = acc[i][0] - xv.x, d1 = acc[i][1] - xv.y;
            float d2 = acc[i][2] - xv.z, d3 = acc[i][3] - xv.w;
            lsum += d0 * d0 + d1 * d1 + d2 * d2 + d3 * d3;
        }
    }
    if (LOSS) {
        __shared__ float smRed[4];
#pragma unroll
        for (int off = 32; off > 0; off >>= 1) lsum += __shfl_down(lsum, off);
        int lane = threadIdx.x & 63, w = threadIdx.x >> 6;
        if (lane == 0) smRed[w] = lsum;
        __syncthreads();
        if (threadIdx.x == 0)
            partial[blockIdx.x] = smRed[0] + smRed[1] + smRed[2] + smRed[3];
    }
}

// ---------------- small matrix transpose ------------------------------------
__global__ __launch_bounds__(256) void transpose_kernel(const float* __restrict__ in,
                                                        float* __restrict__ out,
                                                        int rows, int cols) {
    int i = blockIdx.x * 256 + threadIdx.x;
    if (i >= rows * cols) return;
    int r = i / cols, c = i - r * cols;
    out[c * rows + r] = in[i];
}

// ---------------- attention feature dots (bf16 H): all 4 at once ------------
__global__ __launch_bounds__(256) void attn_f4_kernel(const ushort* __restrict__ Hb,
                                                      const float* __restrict__ va,
                                                      const float* __restrict__ vb,
                                                      const float* __restrict__ pva,
                                                      const float* __restrict__ pvb,
                                                      float* __restrict__ f1,
                                                      float* __restrict__ f2,
                                                      float* __restrict__ pf1,
                                                      float* __restrict__ pf2) {
    int wid = (blockIdx.x * 256 + threadIdx.x) >> 6;  // one wave per row
    int lane = threadIdx.x & 63;
    if (wid >= N_NODES) return;
    uint hv = reinterpret_cast<const uint*>(Hb + (size_t)wid * 128)[lane];
    float x0 = bf2f(hv & 0xffffu);
    float x1 = bf2f(hv >> 16);
    int k = 2 * lane;
    float a = x0 * va[k] + x1 * va[k + 1];
    float b = x0 * vb[k] + x1 * vb[k + 1];
    float pa = x0 * pva[k] + x1 * pva[k + 1];
    float pb = x0 * pvb[k] + x1 * pvb[k + 1];
#pragma unroll
    for (int off = 32; off > 0; off >>= 1) {
        a += __shfl_down(a, off);
        b += __shfl_down(b, off);
        pa += __shfl_down(pa, off);
        pb += __shfl_down(pb, off);
    }
    if (lane == 0) { f1[wid] = a; f2[wid] = b; pf1[wid] = pa; pf2[wid] = pb; }
}

// ---------------- CSR build ------------------------------------------------
__global__ __launch_bounds__(256) void hist_kernel(const int* __restrict__ rows,
                                                   int* __restrict__ deg) {
    int e = blockIdx.x * 256 + threadIdx.x;
    if (e >= N_EDGES) return;
    atomicAdd(&deg[rows[e]], 1);
}

__global__ __launch_bounds__(256) void scan1_kernel(const int* __restrict__ deg,
                                                    int* __restrict__ bsum) {
    __shared__ int sm[256];
    int base = (blockIdx.x * 256 + threadIdx.x) * SCAN_CH;
    int s = 0;
#pragma unroll
    for (int i = 0; i < SCAN_CH; ++i) {
        int idx = base + i;
        if (idx < N_NODES) s += deg[idx];
    }
    sm[threadIdx.x] = s;
    __syncthreads();
    for (int off = 128; off > 0; off >>= 1) {
        if (threadIdx.x < off) sm[threadIdx.x] += sm[threadIdx.x + off];
        __syncthreads();
    }
    if (threadIdx.x == 0) bsum[blockIdx.x] = sm[0];
}

__global__ void scan2_kernel(int* __restrict__ bsum) {
    if (threadIdx.x != 0) return;
    int run = 0;
    for (int i = 0; i < SCAN_NB; ++i) {
        int t = bsum[i];
        bsum[i] = run;
        run += t;
    }
}

__global__ __launch_bounds__(256) void scan3_kernel(const int* __restrict__ deg,
                                                    const int* __restrict__ bsum,
                                                    int* __restrict__ rp) {
    __shared__ int sm[256];
    int base = (blockIdx.x * 256 + threadIdx.x) * SCAN_CH;
    int s = 0;
#pragma unroll
    for (int i = 0; i < SCAN_CH; ++i) {
        int idx = base + i;
        if (idx < N_NODES) s += deg[idx];
    }
    sm[threadIdx.x] = s;
    __syncthreads();
    if (threadIdx.x == 0) {
        int run = bsum[blockIdx.x];
        for (int t = 0; t < 256; ++t) { int tmp = sm[t]; sm[t] = run; run += tmp; }
    }
    __syncthreads();
    int off = sm[threadIdx.x];
#pragma unroll
    for (int i = 0; i < SCAN_CH; ++i) {
        int idx = base + i;
        if (idx < N_NODES) { rp[idx] = off; off += deg[idx]; }
        else if (idx == N_NODES) rp[idx] = off;
    }
}

// scatter edges into CSR slots (packed {col, exp}) + accumulate row sums
__global__ __launch_bounds__(256) void scatter_kernel(const int* __restrict__ rows,
                                                      const int* __restrict__ cols,
                                                      const float* __restrict__ f1,
                                                      const float* __restrict__ f2,
                                                      const int* __restrict__ rp,
                                                      int* __restrict__ cur,
                                                      int2* __restrict__ edg,
                                                      float* __restrict__ s) {
    int e = blockIdx.x * 256 + threadIdx.x;
    if (e >= N_EDGES) return;
    int r = rows[e], c = cols[e];
    float v = __expf(f1[r] + f2[c]);
    int pos = rp[r] + atomicAdd(&cur[r], 1);
    edg[pos] = make_int2(c, __float_as_int(v));
    atomicAdd(&s[r], v);
}

// ---------------- fused SpMM (bf16 gather, unroll-8, both adjacencies) ------
// out = elu(0.2*(A1@H)/s1 + 0.8*(A2@H)/s2); one wave per row, 2 dims/lane
#define SPU 8
__device__ inline void gather_block(const int2* __restrict__ eg, int j,
                                    const uint* __restrict__ Hu, int lane,
                                    float& s0, float& s1) {
    int2 d[SPU];
#pragma unroll
    for (int u = 0; u < SPU; ++u) d[u] = eg[j + u];
    uint h[SPU];
#pragma unroll
    for (int u = 0; u < SPU; ++u) h[u] = Hu[(size_t)d[u].x * 64 + lane];
#pragma unroll
    for (int u = 0; u < SPU; ++u) {
        float v = __int_as_float(d[u].y);
        s0 += v * bf2f(h[u] & 0xffffu);
        s1 += v * bf2f(h[u] >> 16);
    }
}

__global__ __launch_bounds__(256) void spmm_fused_kernel(const int* __restrict__ rp1,
                                                         const int2* __restrict__ eg1,
                                                         const float* __restrict__ s1a,
                                                         const int* __restrict__ rp2,
                                                         const int2* __restrict__ eg2,
                                                         const float* __restrict__ s2a,
                                                         const ushort* __restrict__ Hb,
                                                         float* __restrict__ out) {
    int r = blockIdx.x * 4 + (threadIdx.x >> 6);
    int lane = threadIdx.x & 63;
    const uint* Hu = reinterpret_cast<const uint*>(Hb);
    float a0 = 0.f, a1 = 0.f, b0 = 0.f, b1 = 0.f;
    int j1 = rp1[r], E1 = rp1[r + 1];
    int j2 = rp2[r], E2 = rp2[r + 1];
    while (j1 + SPU <= E1 && j2 + SPU <= E2) {
        int2 d1[SPU], d2[SPU];
#pragma unroll
        for (int u = 0; u < SPU; ++u) d1[u] = eg1[j1 + u];
#pragma unroll
        for (int u = 0; u < SPU; ++u) d2[u] = eg2[j2 + u];
        uint h1[SPU], h2[SPU];
#pragma unroll
        for (int u = 0; u < SPU; ++u) h1[u] = Hu[(size_t)d1[u].x * 64 + lane];
#pragma unroll
        for (int u = 0; u < SPU; ++u) h2[u] = Hu[(size_t)d2[u].x * 64 + lane];
#pragma unroll
        for (int u = 0; u < SPU; ++u) {
            float v1 = __int_as_float(d1[u].y);
            float v2 = __int_as_float(d2[u].y);
            a0 += v1 * bf2f(h1[u] & 0xffffu);
            a1 += v1 * bf2f(h1[u] >> 16);
            b0 += v2 * bf2f(h2[u] & 0xffffu);
            b1 += v2 * bf2f(h2[u] >> 16);
        }
        j1 += SPU; j2 += SPU;
    }
    while (j1 + SPU <= E1) { gather_block(eg1, j1, Hu, lane, a0, a1); j1 += SPU; }
    while (j2 + SPU <= E2) { gather_block(eg2, j2, Hu, lane, b0, b1); j2 += SPU; }
    for (; j1 < E1; ++j1) {
        int2 d = eg1[j1];
        uint h = Hu[(size_t)d.x * 64 + lane];
        float v = __int_as_float(d.y);
        a0 += v * bf2f(h & 0xffffu);
        a1 += v * bf2f(h >> 16);
    }
    for (; j2 < E2; ++j2) {
        int2 d = eg2[j2];
        uint h = Hu[(size_t)d.x * 64 + lane];
        float v = __int_as_float(d.y);
        b0 += v * bf2f(h & 0xffffu);
        b1 += v * bf2f(h >> 16);
    }
    float s1 = s1a[r], s2 = s2a[r];
    float w1 = s1 > 0.f ? 0.2f / s1 : 0.f;
    float w2 = s2 > 0.f ? 0.8f / s2 : 0.f;
    float o0 = w1 * a0 + w2 * b0;
    float o1 = w1 * a1 + w2 * b1;
    o0 = o0 > 0.f ? o0 : expm1f(o0);
    o1 = o1 > 0.f ? o1 : expm1f(o1);
    *reinterpret_cast<float2*>(out + (size_t)r * 128 + 2 * lane) = make_float2(o0, o1);
}

// ---------------- reductions -----------------------------------------------
__global__ __launch_bounds__(256) void sq_reduce_kernel(const float* __restrict__ a,
                                                        float* __restrict__ acc, int n) {
    __shared__ float sm[4];
    float s = 0.f;
    for (int i = blockIdx.x * 256 + threadIdx.x; i < n; i += gridDim.x * 256) {
        float d = a[i];
        s += d * d;
    }
#pragma unroll
    for (int off = 32; off > 0; off >>= 1) s += __shfl_down(s, off);
    int lane = threadIdx.x & 63, w = threadIdx.x >> 6;
    if (lane == 0) sm[w] = s;
    __syncthreads();
    if (threadIdx.x == 0) atomicAdd(acc, sm[0] + sm[1] + sm[2] + sm[3]);
}

__global__ __launch_bounds__(256) void partial_reduce_kernel(const float* __restrict__ p,
                                                             int n, float* __restrict__ acc) {
    __shared__ float sm[4];
    float s = 0.f;
    for (int i = threadIdx.x; i < n; i += 256) s += p[i];
#pragma unroll
    for (int off = 32; off > 0; off >>= 1) s += __shfl_down(s, off);
    int lane = threadIdx.x & 63, w = threadIdx.x >> 6;
    if (lane == 0) sm[w] = s;
    __syncthreads();
    if (threadIdx.x == 0) atomicAdd(acc, sm[0] + sm[1] + sm[2] + sm[3]);
}

__global__ void finalize_kernel(const float* __restrict__ acc, float* __restrict__ out) {
    out[0] = sqrtf(acc[0]) + 1e-4f * (acc[1] + acc[2]);
}

extern "C" void kernel_launch(void* const* d_in, const int* in_sizes, int n_in,
                              void* d_out, int out_size, void* d_ws, size_t ws_size,
                              hipStream_t stream) {
    const float* X    = (const float*)d_in[0];
    const float* W0   = (const float*)d_in[1];
    const float* W1   = (const float*)d_in[2];
    const float* v00  = (const float*)d_in[3];
    const float* v01  = (const float*)d_in[4];
    const float* pv00 = (const float*)d_in[5];
    const float* pv01 = (const float*)d_in[6];
    const int* rows   = (const int*)d_in[7];
    const int* cols   = (const int*)d_in[8];
    const int* prows  = (const int*)d_in[9];
    const int* pcols  = (const int*)d_in[10];

    float* out  = (float*)d_out;
    float* Henc = out + 1;                                  // N x 64 (misaligned base)
    float* Xrec = out + 1 + (size_t)N_NODES * 64;           // N x 256 (misaligned base)

    // scratch carved out of the dead X_ region (fully overwritten at step 8)
    ushort* bufAh = (ushort*)(out + 6400004);               // N x 128 bf16
    int2*  eg1  = (int2*)(out + 12800004);                  // E packed {col, exp}
    int2*  eg2  = (int2*)(out + 16000004);                  // E

    float* ws   = (float*)d_ws;
    float* bufB = ws;                                       // N x 128 fp32
    float* f1   = bufB + (size_t)N_NODES * 128;
    float* f2   = f1 + N_NODES;
    float* pf1  = f2 + N_NODES;
    float* pf2  = pf1 + N_NODES;
    float* s1   = pf2 + N_NODES;                            // N (raw exp row sums)
    float* s2   = s1 + N_NODES;                             // N
    float* acc  = s2 + N_NODES;                             // 4
    float* W1T  = acc + 4;                                  // 64 x 128
    float* W0T  = W1T + 64 * 128;                           // 128 x 256
    int*   rp1  = (int*)(W0T + 128 * 256);                  // N+1
    int*   rp2  = rp1 + N_NODES + 1;                        // N+1
    int*   deg1 = rp2 + N_NODES + 1;                        // N
    int*   cur1 = deg1 + N_NODES;                           // N
    int*   deg2 = cur1 + N_NODES;                           // N
    int*   cur2 = deg2 + N_NODES;                           // N
    int*   bsum = cur2 + N_NODES;                           // SCAN_NB
    float* partial = (float*)(bsum + SCAN_NB);              // n/16 floats

    const int n = N_NODES;
    const int EG = cdiv(N_EDGES, 256);

    // 0. weight transposes (tiny)
    transpose_kernel<<<cdiv(128 * 64, 256), 256, 0, stream>>>(W1, W1T, 128, 64);
    transpose_kernel<<<cdiv(256 * 128, 256), 256, 0, stream>>>(W0, W0T, 256, 128);

    // 1. H1 = X @ W0 -> bufAh (bf16)   [R=32 -> 3125 blocks exact]
    gemm_rb<256, 128, 32, 2, false, false><<<n / 32, 256, 0, stream>>>(
        X, W0, bufAh, nullptr, nullptr, n);

    // zero deg/cur (4N ints), s1/s2 (2N floats) + acc
    hipMemsetAsync(deg1, 0, 4 * (size_t)N_NODES * sizeof(int), stream);
    hipMemsetAsync(s1, 0, (2 * (size_t)N_NODES + 4) * sizeof(float), stream);

    // 2. attention feature dots (one pass over bf16 H1)
    attn_f4_kernel<<<cdiv(n, 4), 256, 0, stream>>>(bufAh, v00, v01, pv00, pv01,
                                                   f1, f2, pf1, pf2);

    // 3. CSR build for both adjacencies (+ raw exp row sums)
    hist_kernel<<<EG, 256, 0, stream>>>(rows, deg1);
    hist_kernel<<<EG, 256, 0, stream>>>(prows, deg2);
    scan1_kernel<<<SCAN_NB, 256, 0, stream>>>(deg1, bsum);
    scan2_kernel<<<1, 64, 0, stream>>>(bsum);
    scan3_kernel<<<SCAN_NB, 256, 0, stream>>>(deg1, bsum, rp1);
    scan1_kernel<<<SCAN_NB, 256, 0, stream>>>(deg2, bsum);
    scan2_kernel<<<1, 64, 0, stream>>>(bsum);
    scan3_kernel<<<SCAN_NB, 256, 0, stream>>>(deg2, bsum, rp2);
    scatter_kernel<<<EG, 256, 0, stream>>>(rows, cols, f1, f2, rp1, cur1, eg1, s1);
    scatter_kernel<<<EG, 256, 0, stream>>>(prows, pcols, pf1, pf2, rp2, cur2, eg2, s2);

    // 4. encoder: bufB = elu(0.2*(A1@H1)/s1 + 0.8*(A2@H1)/s2)
    spmm_fused_kernel<<<n / 4, 256, 0, stream>>>(rp1, eg1, s1, rp2, eg2, s2, bufAh, bufB);

    // 5. Henc = bufB @ W1 -> d_out   [R=64 -> 1563 blocks, guarded]
    gemm_rb<128, 64, 64, 0, false, true><<<cdiv(n, 64), 256, 0, stream>>>(
        bufB, W1, Henc, nullptr, nullptr, n);

    // 6. D0 = Henc @ W1^T -> bufAh (bf16)   [R=32 -> 3125 blocks]
    gemm_rb<64, 128, 32, 2, false, false><<<n / 32, 256, 0, stream>>>(
        Henc, W1T, bufAh, nullptr, nullptr, n);

    // 7. decoder: bufB = elu(0.2*(A1@D0)/s1 + 0.8*(A2@D0)/s2)
    spmm_fused_kernel<<<n / 4, 256, 0, stream>>>(rp1, eg1, s1, rp2, eg2, s2, bufAh, bufB);

    // 8. X_ = bufB @ W0^T -> Xrec, fused loss partials  [R=16 -> 6250 blocks]
    gemm_rb<128, 256, 16, 0, true, false><<<n / 16, 256, 0, stream>>>(
        bufB, W0T, Xrec, X, partial, n);

    // 9. loss
    partial_reduce_kernel<<<1, 256, 0, stream>>>(partial, n / 16, acc + 0);
    sq_reduce_kernel<<<16, 256, 0, stream>>>(W0, acc + 1, 256 * 128);
    sq_reduce_kernel<<<4, 256, 0, stream>>>(W1, acc + 2, 128 * 64);
    finalize_kernel<<<1, 1, 0, stream>>>(acc, out);
}

// Round 8
// 1134.836 us; speedup vs baseline: 5.4312x; 1.0218x over previous
//
#include <hip/hip_runtime.h>
#include <math.h>

#define N_NODES 100000
#define N_EDGES 1600000
#define SCAN_NB 128   // blocks in scan kernels
#define SCAN_CH 4     // elements per thread in scan (128*256*4 = 131072 >= N+1)

static inline int cdiv(long a, long b) { return (int)((a + b - 1) / b); }

typedef unsigned int uint;
typedef unsigned short ushort;

__device__ inline float bf2f(uint u) { return __uint_as_float(u << 16); }
__device__ inline ushort f2bf(float f) {
    uint u = __float_as_uint(f);
    uint r = ((u >> 16) & 1u) + 0x7fffu;   // RNE
    return (ushort)((u + r) >> 16);
}

// ------------- register-blocked GEMM: C[i,m] = sum_k A[i,k]*B[k,m] ----------
// B row-major KxM. Block = 256 threads; tile = R rows x M cols; each thread
// computes 4 rows x 4 cols.
// OUT: 0 = fp32 scalar stores (unaligned base), 1 = fp32 float4 (aligned),
//      2 = bf16 packed, 3 = fp32 scalar to Cv + bf16 packed to Cv2
// ELU: apply elu to outputs before store
// LOSS: fuse sum((C-Xref)^2) per block into partial[blockIdx.x] (needs M==256)
// GUARD: R does not divide nrows -> clamp loads, guard stores
template <int K, int M, int R, int OUT, bool ELU, bool LOSS, bool GUARD>
__global__ __launch_bounds__(256) void gemm_rb(const float* __restrict__ A,
                                               const float* __restrict__ B,
                                               void* __restrict__ Cv,
                                               void* __restrict__ Cv2,
                                               const float* __restrict__ Xref,
                                               float* __restrict__ partial,
                                               int nrows) {
    constexpr int KC = 32;
    constexpr int TPR = M / 4;        // threads spanning M
    constexpr int G = 256 / TPR;      // row-groups of 4 rows
    static_assert(G * 4 == R, "tile geometry");
    __shared__ float Blds[KC * M];
    __shared__ float Alds[KC][R];
    const int tcol = threadIdx.x % TPR;
    const int tg   = threadIdx.x / TPR;
    const int rbase = blockIdx.x * R;
    float acc[4][4] = {};
    for (int k0 = 0; k0 < K; k0 += KC) {
        const float4* Bsrc = reinterpret_cast<const float4*>(B + (size_t)k0 * M);
        float4* Bdst = reinterpret_cast<float4*>(Blds);
#pragma unroll
        for (int i = 0; i < (KC * M / 4) / 256; ++i)
            Bdst[i * 256 + threadIdx.x] = Bsrc[i * 256 + threadIdx.x];
        // A chunk R x KC, stored transposed Alds[k][r]
#pragma unroll
        for (int e = threadIdx.x; e < R * KC; e += 256) {
            int rr = e / KC, kk = e - rr * KC;
            int rg = rbase + rr;
            if (GUARD) rg = min(rg, nrows - 1);
            Alds[kk][rr] = A[(size_t)rg * K + k0 + kk];
        }
        __syncthreads();
#pragma unroll
        for (int kk = 0; kk < KC; ++kk) {
            float4 av = *reinterpret_cast<const float4*>(&Alds[kk][tg * 4]);
            float4 bv = *reinterpret_cast<const float4*>(&Blds[kk * M + tcol * 4]);
            float ar[4] = {av.x, av.y, av.z, av.w};
            float br[4] = {bv.x, bv.y, bv.z, bv.w};
#pragma unroll
            for (int i = 0; i < 4; ++i)
#pragma unroll
                for (int j = 0; j < 4; ++j)
                    acc[i][j] += ar[i] * br[j];
        }
        __syncthreads();
    }
    float lsum = 0.f;
#pragma unroll
    for (int i = 0; i < 4; ++i) {
        int r = rbase + tg * 4 + i;
        if (GUARD && r >= nrows) continue;
        float o0 = acc[i][0], o1 = acc[i][1], o2 = acc[i][2], o3 = acc[i][3];
        if (ELU) {
            o0 = o0 > 0.f ? o0 : expm1f(o0);
            o1 = o1 > 0.f ? o1 : expm1f(o1);
            o2 = o2 > 0.f ? o2 : expm1f(o2);
            o3 = o3 > 0.f ? o3 : expm1f(o3);
        }
        if (OUT == 0 || OUT == 3) {
            float* c = (float*)Cv + (size_t)r * M + tcol * 4;
            c[0] = o0; c[1] = o1; c[2] = o2; c[3] = o3;
        } else if (OUT == 1) {
            float* c = (float*)Cv + (size_t)r * M + tcol * 4;
            *reinterpret_cast<float4*>(c) = make_float4(o0, o1, o2, o3);
        }
        if (OUT == 2 || OUT == 3) {
            void* dst = (OUT == 2) ? Cv : Cv2;
            ushort* c = (ushort*)dst + (size_t)r * M + tcol * 4;
            uint2 w;
            w.x = (uint)f2bf(o0) | ((uint)f2bf(o1) << 16);
            w.y = (uint)f2bf(o2) | ((uint)f2bf(o3) << 16);
            *reinterpret_cast<uint2*>(c) = w;
        }
        if (LOSS) {
            float4 xv = *reinterpret_cast<const float4*>(Xref + (size_t)r * 256 + tcol * 4);
            float d0 = o0 - xv.x, d1 = o1 - xv.y;
            float d2 = o2 - xv.z, d3 = o3 - xv.w;
            lsum += d0 * d0 + d1 * d1 + d2 * d2 + d3 * d3;
        }
    }
    if (LOSS) {
        __shared__ float smRed[4];
#pragma unroll
        for (int off = 32; off > 0; off >>= 1) lsum += __shfl_down(lsum, off);
        int lane = threadIdx.x & 63, w = threadIdx.x >> 6;
        if (lane == 0) smRed[w] = lsum;
        __syncthreads();
        if (threadIdx.x == 0)
            partial[blockIdx.x] = smRed[0] + smRed[1] + smRed[2] + smRed[3];
    }
}

// ---------------- small matrix transpose ------------------------------------
__global__ __launch_bounds__(256) void transpose_kernel(const float* __restrict__ in,
                                                        float* __restrict__ out,
                                                        int rows, int cols) {
    int i = blockIdx.x * 256 + threadIdx.x;
    if (i >= rows * cols) return;
    int r = i / cols, c = i - r * cols;
    out[c * rows + r] = in[i];
}

// ---------------- attention feature dots (bf16 H): all 4 at once ------------
__global__ __launch_bounds__(256) void attn_f4_kernel(const ushort* __restrict__ Hb,
                                                      const float* __restrict__ va,
                                                      const float* __restrict__ vb,
                                                      const float* __restrict__ pva,
                                                      const float* __restrict__ pvb,
                                                      float* __restrict__ f1,
                                                      float* __restrict__ f2,
                                                      float* __restrict__ pf1,
                                                      float* __restrict__ pf2) {
    int wid = (blockIdx.x * 256 + threadIdx.x) >> 6;  // one wave per row
    int lane = threadIdx.x & 63;
    if (wid >= N_NODES) return;
    uint hv = reinterpret_cast<const uint*>(Hb + (size_t)wid * 128)[lane];
    float x0 = bf2f(hv & 0xffffu);
    float x1 = bf2f(hv >> 16);
    int k = 2 * lane;
    float a = x0 * va[k] + x1 * va[k + 1];
    float b = x0 * vb[k] + x1 * vb[k + 1];
    float pa = x0 * pva[k] + x1 * pva[k + 1];
    float pb = x0 * pvb[k] + x1 * pvb[k + 1];
#pragma unroll
    for (int off = 32; off > 0; off >>= 1) {
        a += __shfl_down(a, off);
        b += __shfl_down(b, off);
        pa += __shfl_down(pa, off);
        pb += __shfl_down(pb, off);
    }
    if (lane == 0) { f1[wid] = a; f2[wid] = b; pf1[wid] = pa; pf2[wid] = pb; }
}

// ---------------- CSR build ------------------------------------------------
__global__ __launch_bounds__(256) void hist_kernel(const int* __restrict__ rows,
                                                   int* __restrict__ deg) {
    int e = blockIdx.x * 256 + threadIdx.x;
    if (e >= N_EDGES) return;
    atomicAdd(&deg[rows[e]], 1);
}

__global__ __launch_bounds__(256) void scan1_kernel(const int* __restrict__ deg,
                                                    int* __restrict__ bsum) {
    __shared__ int sm[256];
    int base = (blockIdx.x * 256 + threadIdx.x) * SCAN_CH;
    int s = 0;
#pragma unroll
    for (int i = 0; i < SCAN_CH; ++i) {
        int idx = base + i;
        if (idx < N_NODES) s += deg[idx];
    }
    sm[threadIdx.x] = s;
    __syncthreads();
    for (int off = 128; off > 0; off >>= 1) {
        if (threadIdx.x < off) sm[threadIdx.x] += sm[threadIdx.x + off];
        __syncthreads();
    }
    if (threadIdx.x == 0) bsum[blockIdx.x] = sm[0];
}

__global__ void scan2_kernel(int* __restrict__ bsum) {
    if (threadIdx.x != 0) return;
    int run = 0;
    for (int i = 0; i < SCAN_NB; ++i) {
        int t = bsum[i];
        bsum[i] = run;
        run += t;
    }
}

__global__ __launch_bounds__(256) void scan3_kernel(const int* __restrict__ deg,
                                                    const int* __restrict__ bsum,
                                                    int* __restrict__ rp) {
    __shared__ int sm[256];
    int base = (blockIdx.x * 256 + threadIdx.x) * SCAN_CH;
    int s = 0;
#pragma unroll
    for (int i = 0; i < SCAN_CH; ++i) {
        int idx = base + i;
        if (idx < N_NODES) s += deg[idx];
    }
    sm[threadIdx.x] = s;
    __syncthreads();
    if (threadIdx.x == 0) {
        int run = bsum[blockIdx.x];
        for (int t = 0; t < 256; ++t) { int tmp = sm[t]; sm[t] = run; run += tmp; }
    }
    __syncthreads();
    int off = sm[threadIdx.x];
#pragma unroll
    for (int i = 0; i < SCAN_CH; ++i) {
        int idx = base + i;
        if (idx < N_NODES) { rp[idx] = off; off += deg[idx]; }
        else if (idx == N_NODES) rp[idx] = off;
    }
}

// scatter edges into CSR slots (packed {col, exp}) + accumulate row sums
__global__ __launch_bounds__(256) void scatter_kernel(const int* __restrict__ rows,
                                                      const int* __restrict__ cols,
                                                      const float* __restrict__ f1,
                                                      const float* __restrict__ f2,
                                                      const int* __restrict__ rp,
                                                      int* __restrict__ cur,
                                                      int2* __restrict__ edg,
                                                      float* __restrict__ s) {
    int e = blockIdx.x * 256 + threadIdx.x;
    if (e >= N_EDGES) return;
    int r = rows[e], c = cols[e];
    float v = __expf(f1[r] + f2[c]);
    int pos = rp[r] + atomicAdd(&cur[r], 1);
    edg[pos] = make_int2(c, __float_as_int(v));
    atomicAdd(&s[r], v);
}

// ---------------- fused SpMM on 128-wide bf16 H (encoder) -------------------
// out = elu(0.2*(A1@H)/s1 + 0.8*(A2@H)/s2); one wave per row, 2 dims/lane
#define SPU 8
__device__ inline void gather_block(const int2* __restrict__ eg, int j,
                                    const uint* __restrict__ Hu, int lane,
                                    float& s0, float& s1) {
    int2 d[SPU];
#pragma unroll
    for (int u = 0; u < SPU; ++u) d[u] = eg[j + u];
    uint h[SPU];
#pragma unroll
    for (int u = 0; u < SPU; ++u) h[u] = Hu[(size_t)d[u].x * 64 + lane];
#pragma unroll
    for (int u = 0; u < SPU; ++u) {
        float v = __int_as_float(d[u].y);
        s0 += v * bf2f(h[u] & 0xffffu);
        s1 += v * bf2f(h[u] >> 16);
    }
}

__global__ __launch_bounds__(256) void spmm_fused_kernel(const int* __restrict__ rp1,
                                                         const int2* __restrict__ eg1,
                                                         const float* __restrict__ s1a,
                                                         const int* __restrict__ rp2,
                                                         const int2* __restrict__ eg2,
                                                         const float* __restrict__ s2a,
                                                         const ushort* __restrict__ Hb,
                                                         float* __restrict__ out) {
    int r = blockIdx.x * 4 + (threadIdx.x >> 6);
    int lane = threadIdx.x & 63;
    const uint* Hu = reinterpret_cast<const uint*>(Hb);
    float a0 = 0.f, a1 = 0.f, b0 = 0.f, b1 = 0.f;
    int j1 = rp1[r], E1 = rp1[r + 1];
    int j2 = rp2[r], E2 = rp2[r + 1];
    while (j1 + SPU <= E1 && j2 + SPU <= E2) {
        int2 d1[SPU], d2[SPU];
#pragma unroll
        for (int u = 0; u < SPU; ++u) d1[u] = eg1[j1 + u];
#pragma unroll
        for (int u = 0; u < SPU; ++u) d2[u] = eg2[j2 + u];
        uint h1[SPU], h2[SPU];
#pragma unroll
        for (int u = 0; u < SPU; ++u) h1[u] = Hu[(size_t)d1[u].x * 64 + lane];
#pragma unroll
        for (int u = 0; u < SPU; ++u) h2[u] = Hu[(size_t)d2[u].x * 64 + lane];
#pragma unroll
        for (int u = 0; u < SPU; ++u) {
            float v1 = __int_as_float(d1[u].y);
            float v2 = __int_as_float(d2[u].y);
            a0 += v1 * bf2f(h1[u] & 0xffffu);
            a1 += v1 * bf2f(h1[u] >> 16);
            b0 += v2 * bf2f(h2[u] & 0xffffu);
            b1 += v2 * bf2f(h2[u] >> 16);
        }
        j1 += SPU; j2 += SPU;
    }
    while (j1 + SPU <= E1) { gather_block(eg1, j1, Hu, lane, a0, a1); j1 += SPU; }
    while (j2 + SPU <= E2) { gather_block(eg2, j2, Hu, lane, b0, b1); j2 += SPU; }
    for (; j1 < E1; ++j1) {
        int2 d = eg1[j1];
        uint h = Hu[(size_t)d.x * 64 + lane];
        float v = __int_as_float(d.y);
        a0 += v * bf2f(h & 0xffffu);
        a1 += v * bf2f(h >> 16);
    }
    for (; j2 < E2; ++j2) {
        int2 d = eg2[j2];
        uint h = Hu[(size_t)d.x * 64 + lane];
        float v = __int_as_float(d.y);
        b0 += v * bf2f(h & 0xffffu);
        b1 += v * bf2f(h >> 16);
    }
    float s1 = s1a[r], s2 = s2a[r];
    float w1 = s1 > 0.f ? 0.2f / s1 : 0.f;
    float w2 = s2 > 0.f ? 0.8f / s2 : 0.f;
    float o0 = w1 * a0 + w2 * b0;
    float o1 = w1 * a1 + w2 * b1;
    o0 = o0 > 0.f ? o0 : expm1f(o0);
    o1 = o1 > 0.f ? o1 : expm1f(o1);
    *reinterpret_cast<float2*>(out + (size_t)r * 128 + 2 * lane) = make_float2(o0, o1);
}

// ---------------- fused SpMM on 64-wide bf16 Henc (decoder, no elu) ---------
// S[r] = 0.2*(A1@Henc)[r]/s1[r] + 0.8*(A2@Henc)[r]/s2[r]; 1 dim/lane (ushort)
__device__ inline void gather_block64(const int2* __restrict__ eg, int j,
                                      const ushort* __restrict__ Hb, int lane,
                                      float& s) {
    int2 d[SPU];
#pragma unroll
    for (int u = 0; u < SPU; ++u) d[u] = eg[j + u];
    ushort h[SPU];
#pragma unroll
    for (int u = 0; u < SPU; ++u) h[u] = Hb[(size_t)d[u].x * 64 + lane];
#pragma unroll
    for (int u = 0; u < SPU; ++u)
        s += __int_as_float(d[u].y) * bf2f((uint)h[u]);
}

__global__ __launch_bounds__(256) void spmm64_fused_kernel(const int* __restrict__ rp1,
                                                           const int2* __restrict__ eg1,
                                                           const float* __restrict__ s1a,
                                                           const int* __restrict__ rp2,
                                                           const int2* __restrict__ eg2,
                                                           const float* __restrict__ s2a,
                                                           const ushort* __restrict__ Hb,
                                                           float* __restrict__ S) {
    int r = blockIdx.x * 4 + (threadIdx.x >> 6);
    int lane = threadIdx.x & 63;
    float a = 0.f, b = 0.f;
    int j1 = rp1[r], E1 = rp1[r + 1];
    int j2 = rp2[r], E2 = rp2[r + 1];
    while (j1 + SPU <= E1 && j2 + SPU <= E2) {
        int2 d1[SPU], d2[SPU];
#pragma unroll
        for (int u = 0; u < SPU; ++u) d1[u] = eg1[j1 + u];
#pragma unroll
        for (int u = 0; u < SPU; ++u) d2[u] = eg2[j2 + u];
        ushort h1[SPU], h2[SPU];
#pragma unroll
        for (int u = 0; u < SPU; ++u) h1[u] = Hb[(size_t)d1[u].x * 64 + lane];
#pragma unroll
        for (int u = 0; u < SPU; ++u) h2[u] = Hb[(size_t)d2[u].x * 64 + lane];
#pragma unroll
        for (int u = 0; u < SPU; ++u) {
            a += __int_as_float(d1[u].y) * bf2f((uint)h1[u]);
            b += __int_as_float(d2[u].y) * bf2f((uint)h2[u]);
        }
        j1 += SPU; j2 += SPU;
    }
    while (j1 + SPU <= E1) { gather_block64(eg1, j1, Hb, lane, a); j1 += SPU; }
    while (j2 + SPU <= E2) { gather_block64(eg2, j2, Hb, lane, b); j2 += SPU; }
    for (; j1 < E1; ++j1)
        a += __int_as_float(eg1[j1].y) * bf2f((uint)Hb[(size_t)eg1[j1].x * 64 + lane]);
    for (; j2 < E2; ++j2)
        b += __int_as_float(eg2[j2].y) * bf2f((uint)Hb[(size_t)eg2[j2].x * 64 + lane]);
    float s1 = s1a[r], s2 = s2a[r];
    float w1 = s1 > 0.f ? 0.2f / s1 : 0.f;
    float w2 = s2 > 0.f ? 0.8f / s2 : 0.f;
    S[(size_t)r * 64 + lane] = w1 * a + w2 * b;
}

// ---------------- reductions -----------------------------------------------
__global__ __launch_bounds__(256) void sq_reduce_kernel(const float* __restrict__ a,
                                                        float* __restrict__ acc, int n) {
    __shared__ float sm[4];
    float s = 0.f;
    for (int i = blockIdx.x * 256 + threadIdx.x; i < n; i += gridDim.x * 256) {
        float d = a[i];
        s += d * d;
    }
#pragma unroll
    for (int off = 32; off > 0; off >>= 1) s += __shfl_down(s, off);
    int lane = threadIdx.x & 63, w = threadIdx.x >> 6;
    if (lane == 0) sm[w] = s;
    __syncthreads();
    if (threadIdx.x == 0) atomicAdd(acc, sm[0] + sm[1] + sm[2] + sm[3]);
}

__global__ __launch_bounds__(256) void partial_reduce_kernel(const float* __restrict__ p,
                                                             int n, float* __restrict__ acc) {
    __shared__ float sm[4];
    float s = 0.f;
    for (int i = threadIdx.x; i < n; i += 256) s += p[i];
#pragma unroll
    for (int off = 32; off > 0; off >>= 1) s += __shfl_down(s, off);
    int lane = threadIdx.x & 63, w = threadIdx.x >> 6;
    if (lane == 0) sm[w] = s;
    __syncthreads();
    if (threadIdx.x == 0) atomicAdd(acc, sm[0] + sm[1] + sm[2] + sm[3]);
}

__global__ void finalize_kernel(const float* __restrict__ acc, float* __restrict__ out) {
    out[0] = sqrtf(acc[0]) + 1e-4f * (acc[1] + acc[2]);
}

extern "C" void kernel_launch(void* const* d_in, const int* in_sizes, int n_in,
                              void* d_out, int out_size, void* d_ws, size_t ws_size,
                              hipStream_t stream) {
    const float* X    = (const float*)d_in[0];
    const float* W0   = (const float*)d_in[1];
    const float* W1   = (const float*)d_in[2];
    const float* v00  = (const float*)d_in[3];
    const float* v01  = (const float*)d_in[4];
    const float* pv00 = (const float*)d_in[5];
    const float* pv01 = (const float*)d_in[6];
    const int* rows   = (const int*)d_in[7];
    const int* cols   = (const int*)d_in[8];
    const int* prows  = (const int*)d_in[9];
    const int* pcols  = (const int*)d_in[10];

    float* out  = (float*)d_out;
    float* Henc = out + 1;                                  // N x 64 (misaligned base)
    float* Xrec = out + 1 + (size_t)N_NODES * 64;           // N x 256 (misaligned base)

    // scratch carved out of the dead X_ region [6400001, 32000001):
    //   bufAh  [ 6400004, 12800004)  N x 128 bf16
    //   eg1    [12800004, 16000004)  E int2
    //   eg2    [16000004, 19200004)  E int2
    //   HencB  [19200004, 22400004)  N x 64 bf16
    //   S      [22400004, 28800004)  N x 64 fp32   (was overlapping HencB: bug)
    ushort* bufAh  = (ushort*)(out + 6400004);
    int2*   eg1    = (int2*)(out + 12800004);
    int2*   eg2    = (int2*)(out + 16000004);
    ushort* HencB  = (ushort*)(out + 19200004);
    float*  S      = out + 22400004;

    float* ws   = (float*)d_ws;
    float* bufB = ws;                                       // N x 128 fp32
    float* f1   = bufB + (size_t)N_NODES * 128;
    float* f2   = f1 + N_NODES;
    float* pf1  = f2 + N_NODES;
    float* pf2  = pf1 + N_NODES;
    float* s1   = pf2 + N_NODES;                            // N (raw exp row sums)
    float* s2   = s1 + N_NODES;                             // N
    float* acc  = s2 + N_NODES;                             // 4
    float* W1T  = acc + 4;                                  // 64 x 128
    float* W0T  = W1T + 64 * 128;                           // 128 x 256
    int*   rp1  = (int*)(W0T + 128 * 256);                  // N+1
    int*   rp2  = rp1 + N_NODES + 1;                        // N+1
    int*   deg1 = rp2 + N_NODES + 1;                        // N
    int*   cur1 = deg1 + N_NODES;                           // N
    int*   deg2 = cur1 + N_NODES;                           // N
    int*   cur2 = deg2 + N_NODES;                           // N
    int*   bsum = cur2 + N_NODES;                           // SCAN_NB
    float* partial = (float*)(bsum + SCAN_NB);              // n/16 floats

    const int n = N_NODES;
    const int EG = cdiv(N_EDGES, 256);

    // 0. weight transposes (tiny)
    transpose_kernel<<<cdiv(128 * 64, 256), 256, 0, stream>>>(W1, W1T, 128, 64);
    transpose_kernel<<<cdiv(256 * 128, 256), 256, 0, stream>>>(W0, W0T, 256, 128);

    // 1. H1 = X @ W0 -> bufAh (bf16)
    gemm_rb<256, 128, 32, 2, false, false, false><<<n / 32, 256, 0, stream>>>(
        X, W0, bufAh, nullptr, nullptr, nullptr, n);

    // zero deg/cur (4N ints), s1/s2 (2N floats) + acc
    hipMemsetAsync(deg1, 0, 4 * (size_t)N_NODES * sizeof(int), stream);
    hipMemsetAsync(s1, 0, (2 * (size_t)N_NODES + 4) * sizeof(float), stream);

    // 2. attention feature dots (one pass over bf16 H1)
    attn_f4_kernel<<<cdiv(n, 4), 256, 0, stream>>>(bufAh, v00, v01, pv00, pv01,
                                                   f1, f2, pf1, pf2);

    // 3. CSR build for both adjacencies (+ raw exp row sums)
    hist_kernel<<<EG, 256, 0, stream>>>(rows, deg1);
    hist_kernel<<<EG, 256, 0, stream>>>(prows, deg2);
    scan1_kernel<<<SCAN_NB, 256, 0, stream>>>(deg1, bsum);
    scan2_kernel<<<1, 64, 0, stream>>>(bsum);
    scan3_kernel<<<SCAN_NB, 256, 0, stream>>>(deg1, bsum, rp1);
    scan1_kernel<<<SCAN_NB, 256, 0, stream>>>(deg2, bsum);
    scan2_kernel<<<1, 64, 0, stream>>>(bsum);
    scan3_kernel<<<SCAN_NB, 256, 0, stream>>>(deg2, bsum, rp2);
    scatter_kernel<<<EG, 256, 0, stream>>>(rows, cols, f1, f2, rp1, cur1, eg1, s1);
    scatter_kernel<<<EG, 256, 0, stream>>>(prows, pcols, pf1, pf2, rp2, cur2, eg2, s2);

    // 4. encoder: bufB = elu(0.2*(A1@H1)/s1 + 0.8*(A2@H1)/s2)
    spmm_fused_kernel<<<n / 4, 256, 0, stream>>>(rp1, eg1, s1, rp2, eg2, s2, bufAh, bufB);

    // 5. Henc = bufB @ W1 -> d_out (fp32) + HencB (bf16 for gather)
    gemm_rb<128, 64, 64, 3, false, false, true><<<cdiv(n, 64), 256, 0, stream>>>(
        bufB, W1, Henc, HencB, nullptr, nullptr, n);

    // 6. decoder spmm on Henc (64-wide): S = 0.2*(A1@Henc)/s1 + 0.8*(A2@Henc)/s2
    //    (spmm commutes with @W1T: spmm(A, Henc@W1T) == spmm(A, Henc)@W1T)
    spmm64_fused_kernel<<<n / 4, 256, 0, stream>>>(rp1, eg1, s1, rp2, eg2, s2, HencB, S);

    // 7. D = elu(S @ W1T) -> bufB
    gemm_rb<64, 128, 32, 1, true, false, false><<<n / 32, 256, 0, stream>>>(
        S, W1T, bufB, nullptr, nullptr, nullptr, n);

    // 8. X_ = bufB @ W0T -> Xrec, fused loss partials
    gemm_rb<128, 256, 16, 0, false, true, false><<<n / 16, 256, 0, stream>>>(
        bufB, W0T, Xrec, nullptr, X, partial, n);

    // 9. loss
    partial_reduce_kernel<<<1, 256, 0, stream>>>(partial, n / 16, acc + 0);
    sq_reduce_kernel<<<16, 256, 0, stream>>>(W0, acc + 1, 256 * 128);
    sq_reduce_kernel<<<4, 256, 0, stream>>>(W1, acc + 2, 128 * 64);
    finalize_kernel<<<1, 1, 0, stream>>>(acc, out);
}